// Round 12
// baseline (918.844 us; speedup 1.0000x reference)
//
#include <hip/hip_runtime.h>
#include <math.h>

// ---------------------------------------------------------------------------
// VertexGNN on MI355X — round 11 = R9 (829us, best) + edge block 1024.
// Reverts R10's two regressions (GELU select-form; fused pool_head that
// collapsed pooling parallelism to 256 waves). New: 1024-thread edge blocks
// so 16 waves share one 12KB LDS weight image (was 4) — tests whether
// LDS-per-wave packing is what caps residency at ~9 waves/CU.
// ---------------------------------------------------------------------------

typedef __attribute__((ext_vector_type(8))) short bfrag;   // 8 x bf16
typedef __attribute__((ext_vector_type(4))) float ffrag;   // 4 x f32

template <int CTRL>
__device__ __forceinline__ float dpp_mov(float v) {
  return __int_as_float(
      __builtin_amdgcn_update_dpp(0, __float_as_int(v), CTRL, 0xF, 0xF, true));
}

// sum across the 16 consecutive lanes sharing lane>>4 (DPP row ops, VALU-rate)
__device__ __forceinline__ float rsum16(float v) {
  v += dpp_mov<0x128>(v);   // row_ror:8
  v += dpp_mov<0x124>(v);   // row_ror:4
  v += dpp_mov<0x122>(v);   // row_ror:2
  v += dpp_mov<0x121>(v);   // row_ror:1
  return v;
}

__device__ __forceinline__ float wave_sum64(float v) {
  v = rsum16(v);
  v += __shfl_xor(v, 16, 64);
  v += __shfl_xor(v, 32, 64);
  return v;
}

__device__ __forceinline__ float ln_apply(float t, float g, float b) {
  float mu = wave_sum64(t) * 0.015625f;
  float d = t - mu;
  float var = wave_sum64(d * d) * 0.015625f;
  return d * rsqrtf(var + 1e-5f) * g + b;
}

// A&S 7.1.27: erf(x) ~= 1 - 1/(1+a1x+a2x^2+a3x^3+a4x^4)^4, |err|<=5e-4.
// Single transcendental (v_rcp). Branchless copysign form (R10's select
// variant regressed — keep this one).
__device__ __forceinline__ float erf_fast(float x) {
  float ax = fabsf(x);
  float p = fmaf(fmaf(fmaf(fmaf(0.078108f, ax, 0.000972f), ax, 0.230389f),
                      ax, 0.278393f), ax, 1.0f);
  p = p * p;
  p = p * p;
  float r = __builtin_amdgcn_rcpf(p);
  return copysignf(1.0f - r, x);
}

__device__ __forceinline__ float gelu_exact(float v) {
  float half = 0.5f * v;
  return fmaf(half, erf_fast(v * 0.70710678118654752440f), half);
}

__device__ __forceinline__ float lane_bcast(float v, int k) {
  return __uint_as_float(__builtin_amdgcn_readlane(__float_as_uint(v), k));
}

// float -> bf16 (RNE)
__device__ __forceinline__ short f2bf(float f) {
  union { float f; unsigned u; } v; v.f = f;
  unsigned r = v.u + 0x7fffu + ((v.u >> 16) & 1u);
  return (short)(r >> 16);
}

// ---------- merged init: prep_w | hist | embed ------------------------------
__global__ __launch_bounds__(256) void k_init(
    const float* __restrict__ x,
    const float* __restrict__ w1, const float* __restrict__ b1,
    const float* __restrict__ g1, const float* __restrict__ be1,
    const float* __restrict__ w2, const float* __restrict__ b2,
    const float* __restrict__ g2, const float* __restrict__ be2,
    const float* __restrict__ conv_w, ushort* __restrict__ wt,
    const int* __restrict__ ei, int* __restrict__ csr,
    float* __restrict__ h, ushort* __restrict__ hb,
    int n_nodes, int ne, int oHist, int oEmb, int embWaves) {
  const int bid = blockIdx.x;
  const int tid = threadIdx.x;
  if (bid < oHist) {  // prep_w: 3*64*96 = 18432 elems, 72 blocks
    const int i = bid * 256 + tid;
    const int k = i % 96, f = (i / 96) % 64, l = i / (96 * 64);
    const float v = (k < 66) ? conv_w[(size_t)l * 66 * 64 + k * 64 + f] : 0.0f;
    wt[i] = (ushort)f2bf(v);
    return;
  }
  if (bid < oEmb) {  // degree histogram (csr pre-zeroed by memsetAsync)
    const int i = (bid - oHist) * 256 + tid;
    if (i < ne) atomicAdd(&csr[ei[ne + i]], 1);
    return;
  }
  // ---- node embedding ----
  const int lane = tid & 63;
  const int wid = ((bid - oEmb) * 256 + tid) >> 6;
  const int nw = embWaves;
  float wc[64];
#pragma unroll
  for (int k = 0; k < 64; k++) wc[k] = w2[k * 64 + lane];
  const float w1a = w1[lane], w1b = w1[64 + lane];
  const float vb1 = b1[lane], vg1 = g1[lane], vbe1 = be1[lane];
  const float vb2 = b2[lane], vg2 = g2[lane], vbe2 = be2[lane];
  for (int n = wid; n < n_nodes; n += nw) {
    const float x0 = x[2 * n], x1 = x[2 * n + 1];
    float t = fmaf(x0, w1a, fmaf(x1, w1b, vb1));
    t = gelu_exact(ln_apply(t, vg1, vbe1));
    float a0 = vb2, a1 = 0.f, a2 = 0.f, a3 = 0.f;
#pragma unroll
    for (int k = 0; k < 64; k += 4) {
      a0 = fmaf(lane_bcast(t, k + 0), wc[k + 0], a0);
      a1 = fmaf(lane_bcast(t, k + 1), wc[k + 1], a1);
      a2 = fmaf(lane_bcast(t, k + 2), wc[k + 2], a2);
      a3 = fmaf(lane_bcast(t, k + 3), wc[k + 3], a3);
    }
    float acc = (a0 + a1) + (a2 + a3);
    acc = gelu_exact(ln_apply(acc, vg2, vbe2));
    h[n * 64 + lane] = acc;
    hb[n * 64 + lane] = (ushort)f2bf(acc);
  }
}

// Single-block exclusive scan, int4-vectorized chunks, ~3 barriers total.
__global__ __launch_bounds__(1024) void k_scan_fast(int* __restrict__ buf, int n) {
  __shared__ int wsum[16];
  const int tid = threadIdx.x, lane = tid & 63, w = tid >> 6;
  const int chunk = (((n + 1023) / 1024) + 3) & ~3;   // multiple of 4
  const int a = min(tid * chunk, n), b = min(a + chunk, n);
  const bool full = (a + chunk <= n);
  int s = 0;
  if (full) {
    const int4* p4 = (const int4*)(buf + a);
#pragma unroll 4
    for (int i = 0; i < chunk / 4; i++) {
      int4 v = p4[i];
      s += v.x + v.y + v.z + v.w;
    }
  } else {
    for (int i = a; i < b; i++) s += buf[i];
  }
  int inc = s;
#pragma unroll
  for (int sh = 1; sh < 64; sh <<= 1) {
    int t = __shfl_up(inc, sh, 64);
    if (lane >= sh) inc += t;
  }
  if (lane == 63) wsum[w] = inc;
  __syncthreads();
  int wb = 0;
  for (int j = 0; j < w; j++) wb += wsum[j];
  int excl = wb + inc - s;
  if (full) {
    int4* p4 = (int4*)(buf + a);
#pragma unroll 4
    for (int i = 0; i < chunk / 4; i++) {
      int4 v = p4[i];
      int4 o;
      o.x = excl; excl += v.x;
      o.y = excl; excl += v.y;
      o.z = excl; excl += v.z;
      o.w = excl; excl += v.w;
      p4[i] = o;
    }
  } else {
    for (int i = a; i < b; i++) { int v = buf[i]; buf[i] = excl; excl += v; }
  }
}

__global__ void k_scatter(const int* __restrict__ ei, const float* __restrict__ ea,
                          int* __restrict__ cursor, int2* __restrict__ edata, int ne) {
  int i = blockIdx.x * blockDim.x + threadIdx.x;
  if (i < ne) {
    const int d = ei[ne + i];
    const int s = ei[i];
    const float2 eav = *(const float2*)(ea + 2 * (size_t)i);
    const unsigned pk = (unsigned)(ushort)f2bf(eav.x) |
                        ((unsigned)(ushort)f2bf(eav.y) << 16);
    const int pos = atomicAdd(&cursor[d], 1);
    edata[pos] = make_int2(s, (int)pk);
  }
}

// ---------------- fused edge-message + aggregate + node update --------------
// 1024-thread blocks: 16 waves share one 12KB LDS weight image.
__global__ __launch_bounds__(1024) void k_edge_node(
    const float* __restrict__ h_in, const ushort* __restrict__ hb_in,
    float* __restrict__ h_out, ushort* __restrict__ hb_out,
    const int2* __restrict__ edata, const int* __restrict__ ends,
    const ushort* __restrict__ wt,
    const float* __restrict__ bias, const float* __restrict__ mg,
    const float* __restrict__ mb,
    const float* __restrict__ ng, const float* __restrict__ nb,
    const float* __restrict__ og, const float* __restrict__ ob,
    int n_nodes, int writeHb) {
  __shared__ __align__(16) ushort lwt[64 * 96];   // 12 KB: B^T tiles
  {
    const uint4* s = (const uint4*)wt;
    uint4* d = (uint4*)lwt;
    if (threadIdx.x < 768) d[threadIdx.x] = s[threadIdx.x];
  }
  __syncthreads();

  const int lane = threadIdx.x & 63;
  const int grp = lane >> 4, col = lane & 15;
  const int wid = (blockIdx.x * blockDim.x + threadIdx.x) >> 6;
  const int nw = (gridDim.x * blockDim.x) >> 6;

  float vb[4], vg[4], vbb[4];
#pragma unroll
  for (int t = 0; t < 4; t++) {
    const int f = t * 16 + col;
    vb[t] = bias[f]; vg[t] = mg[f]; vbb[t] = mb[f];
  }

  for (int n = wid; n < n_nodes; n += nw) {
    const int start = (n == 0) ? 0 : ends[n - 1];
    const int end = ends[n];
    float aggf[4] = {0.f, 0.f, 0.f, 0.f};   // lane-local 4-row partials

    int p = start;
    int2 ed = edata[p + min(col, end - p - 1)];
    const ushort* hp0 = hb_in + (size_t)ed.x * 64 + grp * 8;
    bfrag A0 = *(const bfrag*)(hp0);
    bfrag A1 = *(const bfrag*)(hp0 + 32);
    int edy = ed.y;

    for (;;) {
      const int rem = min(16, end - p);
      const int pn = p + 16;
      const bool more = pn < end;
      // prefetch next chunk's payload (safe index when last chunk)
      const int nidx = more ? (pn + min(col, end - pn - 1)) : (p + min(col, rem - 1));
      const int2 edn = edata[nidx];

      bfrag A2 = {0, 0, 0, 0, 0, 0, 0, 0};
      if (grp == 0) {
        A2[0] = (short)(edy & 0xffff);
        A2[1] = (short)((unsigned)edy >> 16);
      }

      ffrag acc[4];
#pragma unroll
      for (int t = 0; t < 4; t++) { ffrag c = {vb[t], vb[t], vb[t], vb[t]}; acc[t] = c; }
#pragma unroll
      for (int t = 0; t < 4; t++) {
        const bfrag B = *(const bfrag*)(lwt + (t * 16 + col) * 96 + grp * 8);
        acc[t] = __builtin_amdgcn_mfma_f32_16x16x32_bf16(A0, B, acc[t], 0, 0, 0);
      }
#pragma unroll
      for (int t = 0; t < 4; t++) {
        const bfrag B = *(const bfrag*)(lwt + (t * 16 + col) * 96 + 32 + grp * 8);
        acc[t] = __builtin_amdgcn_mfma_f32_16x16x32_bf16(A1, B, acc[t], 0, 0, 0);
      }
#pragma unroll
      for (int t = 0; t < 4; t++) {
        const bfrag B = *(const bfrag*)(lwt + (t * 16 + col) * 96 + 64 + grp * 8);
        acc[t] = __builtin_amdgcn_mfma_f32_16x16x32_bf16(A2, B, acc[t], 0, 0, 0);
      }

      // prefetch next chunk's gather so it flies during the epilogue
      const ushort* hq = hb_in + (size_t)edn.x * 64 + grp * 8;
      const bfrag N0 = *(const bfrag*)(hq);
      const bfrag N1 = *(const bfrag*)(hq + 32);

      // ---- per-edge LN stats via E[x] / E[x^2] (rows m = grp*4+r) ----
      float sx[4], sq[4];
#pragma unroll
      for (int r = 0; r < 4; r++) {
        float s = (acc[0][r] + acc[1][r]) + (acc[2][r] + acc[3][r]);
        float q = fmaf(acc[0][r], acc[0][r], fmaf(acc[1][r], acc[1][r],
                  fmaf(acc[2][r], acc[2][r], acc[3][r] * acc[3][r])));
        sx[r] = s; sq[r] = q;
      }
#pragma unroll
      for (int r = 0; r < 4; r++) sx[r] = rsum16(sx[r]);
#pragma unroll
      for (int r = 0; r < 4; r++) sq[r] = rsum16(sq[r]);
      // per-row scale (iv) and shift (mi = -mu*iv), row-valid float mask
      float iv[4], mi[4], mk[4];
#pragma unroll
      for (int r = 0; r < 4; r++) {
        const float mu = sx[r] * 0.015625f;
        const float var = fmaf(-mu, mu, sq[r] * 0.015625f);
        iv[r] = rsqrtf(var + 1e-5f);
        mi[r] = -mu * iv[r];
        mk[r] = (grp * 4 + r < rem) ? 1.0f : 0.0f;
      }

      // ---- LN-apply (2 fma) + GELU + float-masked lane-local row-sum ----
#pragma unroll
      for (int t = 0; t < 4; t++) {
        float rs = 0.f;
#pragma unroll
        for (int r = 0; r < 4; r++) {
          const float z = fmaf(acc[t][r], iv[r], mi[r]);
          float v = fmaf(z, vg[t], vbb[t]);
          v = gelu_exact(v);
          rs = fmaf(v, mk[r], rs);
        }
        aggf[t] += rs;   // cross-grp reduction deferred to after the loop
      }

      if (!more) break;
      p = pn; A0 = N0; A1 = N1; edy = edn.y;
    }

    // deferred cross-grp reduction (linear, once per node)
#pragma unroll
    for (int t = 0; t < 4; t++) {
      float v = aggf[t];
      v += __shfl_xor(v, 16, 64);
      v += __shfl_xor(v, 32, 64);
      aggf[t] = v;
    }

    // agg in feature=lane layout (lane = grp*16+col holds tile t=grp)
    const float aggl = (grp == 0) ? aggf[0] : (grp == 1) ? aggf[1]
                     : (grp == 2) ? aggf[2] : aggf[3];

    const float dg = fmaxf((float)(end - start), 1.0f);
    const float hv = h_in[(size_t)n * 64 + lane];
    const float a = aggl / dg + hv;
    const float c = ln_apply(a, ng[lane], nb[lane]);
    const float o = ln_apply(c, og[lane], ob[lane]);
    const float outv = hv + o;
    h_out[(size_t)n * 64 + lane] = outv;
    if (writeHb) hb_out[(size_t)n * 64 + lane] = (ushort)f2bf(outv);
  }
}

// ------------------------------ pooling (segmented) -------------------------
__global__ void k_pool_seg(const float* __restrict__ h, const int* __restrict__ batch,
                           float* __restrict__ g, float* __restrict__ cnt,
                           int n_nodes, int chunk) {
  const int lane = threadIdx.x & 63;
  const int wid = (blockIdx.x * blockDim.x + threadIdx.x) >> 6;
  const int n0 = wid * chunk;
  if (n0 >= n_nodes) return;
  const int n1 = min(n0 + chunk, n_nodes);
  int cur = batch[n0], c = 0;
  float acc = 0.f;
  for (int n = n0; n < n1; n++) {
    const int b = batch[n];
    if (b != cur) {
      atomicAdd(&g[(size_t)cur * 64 + lane], acc);
      if (lane == 0) atomicAdd(&cnt[cur], (float)c);
      acc = 0.f; c = 0; cur = b;
    }
    acc += h[(size_t)n * 64 + lane];
    c++;
  }
  atomicAdd(&g[(size_t)cur * 64 + lane], acc);
  if (lane == 0) atomicAdd(&cnt[cur], (float)c);
}

// ------------------------------- head --------------------------------------
__global__ void k_head(const float* __restrict__ g, const float* __restrict__ cnt,
                       const float* __restrict__ w1, const float* __restrict__ b1,
                       const float* __restrict__ g1, const float* __restrict__ be1,
                       const float* __restrict__ w2, const float* __restrict__ b2,
                       const float* __restrict__ g2, const float* __restrict__ be2,
                       const float* __restrict__ w3, const float* __restrict__ b3,
                       float* __restrict__ out, int nb_) {
  const int lane = threadIdx.x & 63;
  const int row = (blockIdx.x * blockDim.x + threadIdx.x) >> 6;
  if (row >= nb_) return;
  const float c = fmaxf(cnt[row], 1.0f);
  const float gv = g[row * 64 + lane] / c;
  float a0 = b1[lane], a1 = 0.f, a2 = 0.f, a3 = 0.f;
#pragma unroll
  for (int k = 0; k < 64; k += 4) {
    a0 = fmaf(lane_bcast(gv, k + 0), w1[(k + 0) * 64 + lane], a0);
    a1 = fmaf(lane_bcast(gv, k + 1), w1[(k + 1) * 64 + lane], a1);
    a2 = fmaf(lane_bcast(gv, k + 2), w1[(k + 2) * 64 + lane], a2);
    a3 = fmaf(lane_bcast(gv, k + 3), w1[(k + 3) * 64 + lane], a3);
  }
  float t = (a0 + a1) + (a2 + a3);
  t = fmaxf(ln_apply(t, g1[lane], be1[lane]), 0.0f);

  const int j = lane & 31;
  float c0 = b2[j], c1 = 0.f, c2 = 0.f, c3 = 0.f;
#pragma unroll
  for (int k = 0; k < 64; k += 4) {
    c0 = fmaf(lane_bcast(t, k + 0), w2[(k + 0) * 32 + j], c0);
    c1 = fmaf(lane_bcast(t, k + 1), w2[(k + 1) * 32 + j], c1);
    c2 = fmaf(lane_bcast(t, k + 2), w2[(k + 2) * 32 + j], c2);
    c3 = fmaf(lane_bcast(t, k + 3), w2[(k + 3) * 32 + j], c3);
  }
  float t2 = (c0 + c1) + (c2 + c3);
  t2 = fmaxf(ln_apply(t2, g2[j], be2[j]), 0.0f);
  const float p = t2 * w3[j];
  const float s = wave_sum64(p) * 0.5f;
  if (lane == 0) out[row] = s + b3[0];
}

// ---------------------------------------------------------------------------
extern "C" void kernel_launch(void* const* d_in, const int* in_sizes, int n_in,
                              void* d_out, int out_size, void* d_ws, size_t ws_size,
                              hipStream_t stream) {
  const float* x      = (const float*)d_in[0];
  const float* ea     = (const float*)d_in[1];
  const float* ne_w1  = (const float*)d_in[2];
  const float* ne_b1  = (const float*)d_in[3];
  const float* ne_g1  = (const float*)d_in[4];
  const float* ne_be1 = (const float*)d_in[5];
  const float* ne_w2  = (const float*)d_in[6];
  const float* ne_b2  = (const float*)d_in[7];
  const float* ne_g2  = (const float*)d_in[8];
  const float* ne_be2 = (const float*)d_in[9];
  const float* conv_w = (const float*)d_in[10];
  const float* conv_b = (const float*)d_in[11];
  const float* conv_mg= (const float*)d_in[12];
  const float* conv_mb= (const float*)d_in[13];
  const float* conv_ng= (const float*)d_in[14];
  const float* conv_nb= (const float*)d_in[15];
  const float* out_ng = (const float*)d_in[16];
  const float* out_nb = (const float*)d_in[17];
  const float* m_w1   = (const float*)d_in[18];
  const float* m_b1   = (const float*)d_in[19];
  const float* m_g1   = (const float*)d_in[20];
  const float* m_be1  = (const float*)d_in[21];
  const float* m_w2   = (const float*)d_in[22];
  const float* m_b2   = (const float*)d_in[23];
  const float* m_g2   = (const float*)d_in[24];
  const float* m_be2  = (const float*)d_in[25];
  const float* m_w3   = (const float*)d_in[26];
  const float* m_b3   = (const float*)d_in[27];
  const int*   eidx   = (const int*)d_in[28];
  const int*   batch  = (const int*)d_in[29];
  float* outp = (float*)d_out;

  const int NN = in_sizes[29];
  const int NE = in_sizes[1] / 2;
  const int NB = out_size;

  float* ws = (float*)d_ws;
  float*  h0   = ws;                                  // NN*64 f32
  float*  h1   = h0 + (size_t)NN * 64;                // NN*64 f32
  float*  gbuf = h1 + (size_t)NN * 64;                // NB*64 f32
  float*  cnt  = gbuf + (size_t)NB * 64;              // NB f32
  ushort* wt   = (ushort*)(cnt + NB);                 // 3*64*96 bf16
  ushort* hb0  = wt + 3 * 64 * 96;                    // NN*64 bf16
  ushort* hb1  = hb0 + (size_t)NN * 64;               // NN*64 bf16
  int*    csr  = (int*)(hb1 + (size_t)NN * 64);       // NN int
  int2*   edata= (int2*)(csr + NN);                   // NE int2

  const dim3 blk(256);

  // zero csr + gbuf + cnt
  hipMemsetAsync(csr, 0, sizeof(int) * (size_t)NN, stream);
  hipMemsetAsync(gbuf, 0, sizeof(float) * ((size_t)NB * 64 + NB), stream);

  // merged init: prep(72) | hist | embed(2048 blocks)
  const int nPrep = (3 * 64 * 96) / 256;              // 72
  const int nHist = (NE + 255) / 256;
  const int oHist = nPrep, oEmb = nPrep + nHist;
  const int embBlocks = 2048;
  k_init<<<oEmb + embBlocks, blk, 0, stream>>>(
      x, ne_w1, ne_b1, ne_g1, ne_be1, ne_w2, ne_b2, ne_g2, ne_be2,
      conv_w, wt, eidx, csr, h0, hb0, NN, NE, oHist, oEmb, embBlocks * 4);

  k_scan_fast<<<1, 1024, 0, stream>>>(csr, NN);
  k_scatter<<<(NE + 255) / 256, blk, 0, stream>>>(eidx, ea, csr, edata, NE);

  float* hin = h0;  float* hout = h1;
  ushort* hbin = hb0; ushort* hbout = hb1;
  for (int l = 0; l < 3; l++) {
    k_edge_node<<<1024, dim3(1024), 0, stream>>>(
        hin, hbin, hout, hbout, edata, csr, wt + (size_t)l * 64 * 96,
        conv_b + l * 64, conv_mg + l * 64, conv_mb + l * 64,
        conv_ng + l * 64, conv_nb + l * 64,
        out_ng + l * 64, out_nb + l * 64, NN, (l < 2) ? 1 : 0);
    float* tf = hin; hin = hout; hout = tf;
    ushort* tb = hbin; hbin = hbout; hbout = tb;
  }

  {
    const int chunk = 32;
    const int nwaves = (NN + chunk - 1) / chunk;
    const int nblocks = (nwaves * 64 + 255) / 256;
    k_pool_seg<<<nblocks, blk, 0, stream>>>(hin, batch, gbuf, cnt, NN, chunk);
  }
  k_head<<<(NB + 3) / 4, blk, 0, stream>>>(gbuf, cnt, m_w1, m_b1, m_g1, m_be1,
                                           m_w2, m_b2, m_g2, m_be2, m_w3, m_b3,
                                           outp, NB);
}

// Round 13
// 817.428 us; speedup vs baseline: 1.1241x; 1.1241x over previous
//
#include <hip/hip_runtime.h>
#include <math.h>

// ---------------------------------------------------------------------------
// VertexGNN on MI355X — round 12 = exact R9 (829us best) + three trims:
// - ln_apply via parallel E[x]/E[x^2] wave reductions (chains overlap).
// - workspace reordered so gbuf|cnt|csr share one memset dispatch.
// - ends[n-1..n] fetched as one int2.
// Edge kernel locked at (256,3), grid 4096, 12KB LDS weights (R7/R8/R11
// establish: needs ~170 regs, any tighter cap spills; ~3 waves/SIMD ceiling).
// ---------------------------------------------------------------------------

typedef __attribute__((ext_vector_type(8))) short bfrag;   // 8 x bf16
typedef __attribute__((ext_vector_type(4))) float ffrag;   // 4 x f32

template <int CTRL>
__device__ __forceinline__ float dpp_mov(float v) {
  return __int_as_float(
      __builtin_amdgcn_update_dpp(0, __float_as_int(v), CTRL, 0xF, 0xF, true));
}

// sum across the 16 consecutive lanes sharing lane>>4 (DPP row ops, VALU-rate)
__device__ __forceinline__ float rsum16(float v) {
  v += dpp_mov<0x128>(v);   // row_ror:8
  v += dpp_mov<0x124>(v);   // row_ror:4
  v += dpp_mov<0x122>(v);   // row_ror:2
  v += dpp_mov<0x121>(v);   // row_ror:1
  return v;
}

__device__ __forceinline__ float wave_sum64(float v) {
  v = rsum16(v);
  v += __shfl_xor(v, 16, 64);
  v += __shfl_xor(v, 32, 64);
  return v;
}

// LN with independent E[x], E[x^2] reductions (chains overlap in the pipe)
__device__ __forceinline__ float ln_apply(float t, float g, float b) {
  float s1 = wave_sum64(t);
  float s2 = wave_sum64(t * t);
  float mu = s1 * 0.015625f;
  float var = fmaf(-mu, mu, s2 * 0.015625f);
  return (t - mu) * rsqrtf(var + 1e-5f) * g + b;
}

// A&S 7.1.27: erf(x) ~= 1 - 1/poly^4, |err|<=5e-4; single v_rcp.
__device__ __forceinline__ float erf_fast(float x) {
  float ax = fabsf(x);
  float p = fmaf(fmaf(fmaf(fmaf(0.078108f, ax, 0.000972f), ax, 0.230389f),
                      ax, 0.278393f), ax, 1.0f);
  p = p * p;
  p = p * p;
  float r = __builtin_amdgcn_rcpf(p);
  return copysignf(1.0f - r, x);
}

__device__ __forceinline__ float gelu_exact(float v) {
  float half = 0.5f * v;
  return fmaf(half, erf_fast(v * 0.70710678118654752440f), half);
}

__device__ __forceinline__ float lane_bcast(float v, int k) {
  return __uint_as_float(__builtin_amdgcn_readlane(__float_as_uint(v), k));
}

// float -> bf16 (RNE)
__device__ __forceinline__ short f2bf(float f) {
  union { float f; unsigned u; } v; v.f = f;
  unsigned r = v.u + 0x7fffu + ((v.u >> 16) & 1u);
  return (short)(r >> 16);
}

// ---------- merged init: prep_w | hist | embed ------------------------------
__global__ __launch_bounds__(256) void k_init(
    const float* __restrict__ x,
    const float* __restrict__ w1, const float* __restrict__ b1,
    const float* __restrict__ g1, const float* __restrict__ be1,
    const float* __restrict__ w2, const float* __restrict__ b2,
    const float* __restrict__ g2, const float* __restrict__ be2,
    const float* __restrict__ conv_w, ushort* __restrict__ wt,
    const int* __restrict__ ei, int* __restrict__ csr,
    float* __restrict__ h, ushort* __restrict__ hb,
    int n_nodes, int ne, int oHist, int oEmb, int embWaves) {
  const int bid = blockIdx.x;
  const int tid = threadIdx.x;
  if (bid < oHist) {  // prep_w: 3*64*96 = 18432 elems, 72 blocks
    const int i = bid * 256 + tid;
    const int k = i % 96, f = (i / 96) % 64, l = i / (96 * 64);
    const float v = (k < 66) ? conv_w[(size_t)l * 66 * 64 + k * 64 + f] : 0.0f;
    wt[i] = (ushort)f2bf(v);
    return;
  }
  if (bid < oEmb) {  // degree histogram (csr pre-zeroed by memsetAsync)
    const int i = (bid - oHist) * 256 + tid;
    if (i < ne) atomicAdd(&csr[ei[ne + i]], 1);
    return;
  }
  // ---- node embedding ----
  const int lane = tid & 63;
  const int wid = ((bid - oEmb) * 256 + tid) >> 6;
  const int nw = embWaves;
  float wc[64];
#pragma unroll
  for (int k = 0; k < 64; k++) wc[k] = w2[k * 64 + lane];
  const float w1a = w1[lane], w1b = w1[64 + lane];
  const float vb1 = b1[lane], vg1 = g1[lane], vbe1 = be1[lane];
  const float vb2 = b2[lane], vg2 = g2[lane], vbe2 = be2[lane];
  for (int n = wid; n < n_nodes; n += nw) {
    const float x0 = x[2 * n], x1 = x[2 * n + 1];
    float t = fmaf(x0, w1a, fmaf(x1, w1b, vb1));
    t = gelu_exact(ln_apply(t, vg1, vbe1));
    float a0 = vb2, a1 = 0.f, a2 = 0.f, a3 = 0.f;
#pragma unroll
    for (int k = 0; k < 64; k += 4) {
      a0 = fmaf(lane_bcast(t, k + 0), wc[k + 0], a0);
      a1 = fmaf(lane_bcast(t, k + 1), wc[k + 1], a1);
      a2 = fmaf(lane_bcast(t, k + 2), wc[k + 2], a2);
      a3 = fmaf(lane_bcast(t, k + 3), wc[k + 3], a3);
    }
    float acc = (a0 + a1) + (a2 + a3);
    acc = gelu_exact(ln_apply(acc, vg2, vbe2));
    h[n * 64 + lane] = acc;
    hb[n * 64 + lane] = (ushort)f2bf(acc);
  }
}

// Single-block exclusive scan, int4-vectorized chunks, ~3 barriers total.
__global__ __launch_bounds__(1024) void k_scan_fast(int* __restrict__ buf, int n) {
  __shared__ int wsum[16];
  const int tid = threadIdx.x, lane = tid & 63, w = tid >> 6;
  const int chunk = (((n + 1023) / 1024) + 3) & ~3;   // multiple of 4
  const int a = min(tid * chunk, n), b = min(a + chunk, n);
  const bool full = (a + chunk <= n);
  int s = 0;
  if (full) {
    const int4* p4 = (const int4*)(buf + a);
#pragma unroll 4
    for (int i = 0; i < chunk / 4; i++) {
      int4 v = p4[i];
      s += v.x + v.y + v.z + v.w;
    }
  } else {
    for (int i = a; i < b; i++) s += buf[i];
  }
  int inc = s;
#pragma unroll
  for (int sh = 1; sh < 64; sh <<= 1) {
    int t = __shfl_up(inc, sh, 64);
    if (lane >= sh) inc += t;
  }
  if (lane == 63) wsum[w] = inc;
  __syncthreads();
  int wb = 0;
  for (int j = 0; j < w; j++) wb += wsum[j];
  int excl = wb + inc - s;
  if (full) {
    int4* p4 = (int4*)(buf + a);
#pragma unroll 4
    for (int i = 0; i < chunk / 4; i++) {
      int4 v = p4[i];
      int4 o;
      o.x = excl; excl += v.x;
      o.y = excl; excl += v.y;
      o.z = excl; excl += v.z;
      o.w = excl; excl += v.w;
      p4[i] = o;
    }
  } else {
    for (int i = a; i < b; i++) { int v = buf[i]; buf[i] = excl; excl += v; }
  }
}

__global__ void k_scatter(const int* __restrict__ ei, const float* __restrict__ ea,
                          int* __restrict__ cursor, int2* __restrict__ edata, int ne) {
  int i = blockIdx.x * blockDim.x + threadIdx.x;
  if (i < ne) {
    const int d = ei[ne + i];
    const int s = ei[i];
    const float2 eav = *(const float2*)(ea + 2 * (size_t)i);
    const unsigned pk = (unsigned)(ushort)f2bf(eav.x) |
                        ((unsigned)(ushort)f2bf(eav.y) << 16);
    const int pos = atomicAdd(&cursor[d], 1);
    edata[pos] = make_int2(s, (int)pk);
  }
}

// ---------------- fused edge-message + aggregate + node update --------------
__global__ __launch_bounds__(256, 3) void k_edge_node(
    const float* __restrict__ h_in, const ushort* __restrict__ hb_in,
    float* __restrict__ h_out, ushort* __restrict__ hb_out,
    const int2* __restrict__ edata, const int* __restrict__ ends,
    const ushort* __restrict__ wt,
    const float* __restrict__ bias, const float* __restrict__ mg,
    const float* __restrict__ mb,
    const float* __restrict__ ng, const float* __restrict__ nb,
    const float* __restrict__ og, const float* __restrict__ ob,
    int n_nodes, int writeHb) {
  __shared__ __align__(16) ushort lwt[64 * 96];   // 12 KB: B^T tiles
  {
    const uint4* s = (const uint4*)wt;
    uint4* d = (uint4*)lwt;
    for (int i = threadIdx.x; i < 768; i += 256) d[i] = s[i];
  }
  __syncthreads();

  const int lane = threadIdx.x & 63;
  const int grp = lane >> 4, col = lane & 15;
  const int wid = (blockIdx.x * blockDim.x + threadIdx.x) >> 6;
  const int nw = (gridDim.x * blockDim.x) >> 6;

  float vb[4], vg[4], vbb[4];
#pragma unroll
  for (int t = 0; t < 4; t++) {
    const int f = t * 16 + col;
    vb[t] = bias[f]; vg[t] = mg[f]; vbb[t] = mb[f];
  }

  for (int n = wid; n < n_nodes; n += nw) {
    int start, end;
    if (n == 0) {
      start = 0; end = ends[0];
    } else {
      const int2 se = *(const int2*)(ends + n - 1);
      start = se.x; end = se.y;
    }
    float aggf[4] = {0.f, 0.f, 0.f, 0.f};   // lane-local 4-row partials

    int p = start;
    int2 ed = edata[p + min(col, end - p - 1)];
    const ushort* hp0 = hb_in + (size_t)ed.x * 64 + grp * 8;
    bfrag A0 = *(const bfrag*)(hp0);
    bfrag A1 = *(const bfrag*)(hp0 + 32);
    int edy = ed.y;

    for (;;) {
      const int rem = min(16, end - p);
      const int pn = p + 16;
      const bool more = pn < end;
      // prefetch next chunk's payload (safe index when last chunk)
      const int nidx = more ? (pn + min(col, end - pn - 1)) : (p + min(col, rem - 1));
      const int2 edn = edata[nidx];

      bfrag A2 = {0, 0, 0, 0, 0, 0, 0, 0};
      if (grp == 0) {
        A2[0] = (short)(edy & 0xffff);
        A2[1] = (short)((unsigned)edy >> 16);
      }

      ffrag acc[4];
#pragma unroll
      for (int t = 0; t < 4; t++) { ffrag c = {vb[t], vb[t], vb[t], vb[t]}; acc[t] = c; }
#pragma unroll
      for (int t = 0; t < 4; t++) {
        const bfrag B = *(const bfrag*)(lwt + (t * 16 + col) * 96 + grp * 8);
        acc[t] = __builtin_amdgcn_mfma_f32_16x16x32_bf16(A0, B, acc[t], 0, 0, 0);
      }
#pragma unroll
      for (int t = 0; t < 4; t++) {
        const bfrag B = *(const bfrag*)(lwt + (t * 16 + col) * 96 + 32 + grp * 8);
        acc[t] = __builtin_amdgcn_mfma_f32_16x16x32_bf16(A1, B, acc[t], 0, 0, 0);
      }
#pragma unroll
      for (int t = 0; t < 4; t++) {
        const bfrag B = *(const bfrag*)(lwt + (t * 16 + col) * 96 + 64 + grp * 8);
        acc[t] = __builtin_amdgcn_mfma_f32_16x16x32_bf16(A2, B, acc[t], 0, 0, 0);
      }

      // prefetch next chunk's gather so it flies during the epilogue
      const ushort* hq = hb_in + (size_t)edn.x * 64 + grp * 8;
      const bfrag N0 = *(const bfrag*)(hq);
      const bfrag N1 = *(const bfrag*)(hq + 32);

      // ---- per-edge LN stats via E[x] / E[x^2] (rows m = grp*4+r) ----
      float sx[4], sq[4];
#pragma unroll
      for (int r = 0; r < 4; r++) {
        float s = (acc[0][r] + acc[1][r]) + (acc[2][r] + acc[3][r]);
        float q = fmaf(acc[0][r], acc[0][r], fmaf(acc[1][r], acc[1][r],
                  fmaf(acc[2][r], acc[2][r], acc[3][r] * acc[3][r])));
        sx[r] = s; sq[r] = q;
      }
#pragma unroll
      for (int r = 0; r < 4; r++) sx[r] = rsum16(sx[r]);
#pragma unroll
      for (int r = 0; r < 4; r++) sq[r] = rsum16(sq[r]);
      // per-row scale (iv) and shift (mi = -mu*iv), row-valid float mask
      float iv[4], mi[4], mk[4];
#pragma unroll
      for (int r = 0; r < 4; r++) {
        const float mu = sx[r] * 0.015625f;
        const float var = fmaf(-mu, mu, sq[r] * 0.015625f);
        iv[r] = rsqrtf(var + 1e-5f);
        mi[r] = -mu * iv[r];
        mk[r] = (grp * 4 + r < rem) ? 1.0f : 0.0f;
      }

      // ---- LN-apply (2 fma) + GELU + float-masked lane-local row-sum ----
#pragma unroll
      for (int t = 0; t < 4; t++) {
        float rs = 0.f;
#pragma unroll
        for (int r = 0; r < 4; r++) {
          const float z = fmaf(acc[t][r], iv[r], mi[r]);
          float v = fmaf(z, vg[t], vbb[t]);
          v = gelu_exact(v);
          rs = fmaf(v, mk[r], rs);
        }
        aggf[t] += rs;   // cross-grp reduction deferred to after the loop
      }

      if (!more) break;
      p = pn; A0 = N0; A1 = N1; edy = edn.y;
    }

    // deferred cross-grp reduction (linear, once per node)
#pragma unroll
    for (int t = 0; t < 4; t++) {
      float v = aggf[t];
      v += __shfl_xor(v, 16, 64);
      v += __shfl_xor(v, 32, 64);
      aggf[t] = v;
    }

    // agg in feature=lane layout (lane = grp*16+col holds tile t=grp)
    const float aggl = (grp == 0) ? aggf[0] : (grp == 1) ? aggf[1]
                     : (grp == 2) ? aggf[2] : aggf[3];

    const float dg = fmaxf((float)(end - start), 1.0f);
    const float hv = h_in[(size_t)n * 64 + lane];
    const float a = aggl / dg + hv;
    const float c = ln_apply(a, ng[lane], nb[lane]);
    const float o = ln_apply(c, og[lane], ob[lane]);
    const float outv = hv + o;
    h_out[(size_t)n * 64 + lane] = outv;
    if (writeHb) hb_out[(size_t)n * 64 + lane] = (ushort)f2bf(outv);
  }
}

// ------------------------------ pooling (segmented) -------------------------
__global__ void k_pool_seg(const float* __restrict__ h, const int* __restrict__ batch,
                           float* __restrict__ g, float* __restrict__ cnt,
                           int n_nodes, int chunk) {
  const int lane = threadIdx.x & 63;
  const int wid = (blockIdx.x * blockDim.x + threadIdx.x) >> 6;
  const int n0 = wid * chunk;
  if (n0 >= n_nodes) return;
  const int n1 = min(n0 + chunk, n_nodes);
  int cur = batch[n0], c = 0;
  float acc = 0.f;
  for (int n = n0; n < n1; n++) {
    const int b = batch[n];
    if (b != cur) {
      atomicAdd(&g[(size_t)cur * 64 + lane], acc);
      if (lane == 0) atomicAdd(&cnt[cur], (float)c);
      acc = 0.f; c = 0; cur = b;
    }
    acc += h[(size_t)n * 64 + lane];
    c++;
  }
  atomicAdd(&g[(size_t)cur * 64 + lane], acc);
  if (lane == 0) atomicAdd(&cnt[cur], (float)c);
}

// ------------------------------- head --------------------------------------
__global__ void k_head(const float* __restrict__ g, const float* __restrict__ cnt,
                       const float* __restrict__ w1, const float* __restrict__ b1,
                       const float* __restrict__ g1, const float* __restrict__ be1,
                       const float* __restrict__ w2, const float* __restrict__ b2,
                       const float* __restrict__ g2, const float* __restrict__ be2,
                       const float* __restrict__ w3, const float* __restrict__ b3,
                       float* __restrict__ out, int nb_) {
  const int lane = threadIdx.x & 63;
  const int row = (blockIdx.x * blockDim.x + threadIdx.x) >> 6;
  if (row >= nb_) return;
  const float c = fmaxf(cnt[row], 1.0f);
  const float gv = g[row * 64 + lane] / c;
  float a0 = b1[lane], a1 = 0.f, a2 = 0.f, a3 = 0.f;
#pragma unroll
  for (int k = 0; k < 64; k += 4) {
    a0 = fmaf(lane_bcast(gv, k + 0), w1[(k + 0) * 64 + lane], a0);
    a1 = fmaf(lane_bcast(gv, k + 1), w1[(k + 1) * 64 + lane], a1);
    a2 = fmaf(lane_bcast(gv, k + 2), w1[(k + 2) * 64 + lane], a2);
    a3 = fmaf(lane_bcast(gv, k + 3), w1[(k + 3) * 64 + lane], a3);
  }
  float t = (a0 + a1) + (a2 + a3);
  t = fmaxf(ln_apply(t, g1[lane], be1[lane]), 0.0f);

  const int j = lane & 31;
  float c0 = b2[j], c1 = 0.f, c2 = 0.f, c3 = 0.f;
#pragma unroll
  for (int k = 0; k < 64; k += 4) {
    c0 = fmaf(lane_bcast(t, k + 0), w2[(k + 0) * 32 + j], c0);
    c1 = fmaf(lane_bcast(t, k + 1), w2[(k + 1) * 32 + j], c1);
    c2 = fmaf(lane_bcast(t, k + 2), w2[(k + 2) * 32 + j], c2);
    c3 = fmaf(lane_bcast(t, k + 3), w2[(k + 3) * 32 + j], c3);
  }
  float t2 = (c0 + c1) + (c2 + c3);
  t2 = fmaxf(ln_apply(t2, g2[j], be2[j]), 0.0f);
  const float p = t2 * w3[j];
  const float s = wave_sum64(p) * 0.5f;
  if (lane == 0) out[row] = s + b3[0];
}

// ---------------------------------------------------------------------------
extern "C" void kernel_launch(void* const* d_in, const int* in_sizes, int n_in,
                              void* d_out, int out_size, void* d_ws, size_t ws_size,
                              hipStream_t stream) {
  const float* x      = (const float*)d_in[0];
  const float* ea     = (const float*)d_in[1];
  const float* ne_w1  = (const float*)d_in[2];
  const float* ne_b1  = (const float*)d_in[3];
  const float* ne_g1  = (const float*)d_in[4];
  const float* ne_be1 = (const float*)d_in[5];
  const float* ne_w2  = (const float*)d_in[6];
  const float* ne_b2  = (const float*)d_in[7];
  const float* ne_g2  = (const float*)d_in[8];
  const float* ne_be2 = (const float*)d_in[9];
  const float* conv_w = (const float*)d_in[10];
  const float* conv_b = (const float*)d_in[11];
  const float* conv_mg= (const float*)d_in[12];
  const float* conv_mb= (const float*)d_in[13];
  const float* conv_ng= (const float*)d_in[14];
  const float* conv_nb= (const float*)d_in[15];
  const float* out_ng = (const float*)d_in[16];
  const float* out_nb = (const float*)d_in[17];
  const float* m_w1   = (const float*)d_in[18];
  const float* m_b1   = (const float*)d_in[19];
  const float* m_g1   = (const float*)d_in[20];
  const float* m_be1  = (const float*)d_in[21];
  const float* m_w2   = (const float*)d_in[22];
  const float* m_b2   = (const float*)d_in[23];
  const float* m_g2   = (const float*)d_in[24];
  const float* m_be2  = (const float*)d_in[25];
  const float* m_w3   = (const float*)d_in[26];
  const float* m_b3   = (const float*)d_in[27];
  const int*   eidx   = (const int*)d_in[28];
  const int*   batch  = (const int*)d_in[29];
  float* outp = (float*)d_out;

  const int NN = in_sizes[29];
  const int NE = in_sizes[1] / 2;
  const int NB = out_size;

  float* ws = (float*)d_ws;
  float*  h0   = ws;                                  // NN*64 f32
  float*  h1   = h0 + (size_t)NN * 64;                // NN*64 f32
  float*  gbuf = h1 + (size_t)NN * 64;                // NB*64 f32  --+
  float*  cnt  = gbuf + (size_t)NB * 64;              // NB f32       | one
  int*    csr  = (int*)(cnt + NB);                    // NN int     --+ memset
  ushort* wt   = (ushort*)(csr + NN);                 // 3*64*96 bf16
  ushort* hb0  = wt + 3 * 64 * 96;                    // NN*64 bf16
  ushort* hb1  = hb0 + (size_t)NN * 64;               // NN*64 bf16
  int2*   edata= (int2*)(hb1 + (size_t)NN * 64);      // NE int2

  const dim3 blk(256);

  // zero gbuf + cnt + csr in one contiguous memset
  hipMemsetAsync(gbuf, 0, sizeof(float) * ((size_t)NB * 64 + NB) +
                          sizeof(int) * (size_t)NN, stream);

  // merged init: prep(72) | hist | embed(2048 blocks)
  const int nPrep = (3 * 64 * 96) / 256;              // 72
  const int nHist = (NE + 255) / 256;
  const int oHist = nPrep, oEmb = nPrep + nHist;
  const int embBlocks = 2048;
  k_init<<<oEmb + embBlocks, blk, 0, stream>>>(
      x, ne_w1, ne_b1, ne_g1, ne_be1, ne_w2, ne_b2, ne_g2, ne_be2,
      conv_w, wt, eidx, csr, h0, hb0, NN, NE, oHist, oEmb, embBlocks * 4);

  k_scan_fast<<<1, 1024, 0, stream>>>(csr, NN);
  k_scatter<<<(NE + 255) / 256, blk, 0, stream>>>(eidx, ea, csr, edata, NE);

  float* hin = h0;  float* hout = h1;
  ushort* hbin = hb0; ushort* hbout = hb1;
  for (int l = 0; l < 3; l++) {
    k_edge_node<<<4096, blk, 0, stream>>>(
        hin, hbin, hout, hbout, edata, csr, wt + (size_t)l * 64 * 96,
        conv_b + l * 64, conv_mg + l * 64, conv_mb + l * 64,
        conv_ng + l * 64, conv_nb + l * 64,
        out_ng + l * 64, out_nb + l * 64, NN, (l < 2) ? 1 : 0);
    float* tf = hin; hin = hout; hout = tf;
    ushort* tb = hbin; hbin = hbout; hbout = tb;
  }

  {
    const int chunk = 32;
    const int nwaves = (NN + chunk - 1) / chunk;
    const int nblocks = (nwaves * 64 + 255) / 256;
    k_pool_seg<<<nblocks, blk, 0, stream>>>(hin, batch, gbuf, cnt, NN, chunk);
  }
  k_head<<<(NB + 3) / 4, blk, 0, stream>>>(gbuf, cnt, m_w1, m_b1, m_g1, m_be1,
                                           m_w2, m_b2, m_g2, m_be2, m_w3, m_b3,
                                           outp, NB);
}

// Round 14
// 766.208 us; speedup vs baseline: 1.1992x; 1.0668x over previous
//
#include <hip/hip_runtime.h>
#include <math.h>

// ---------------------------------------------------------------------------
// VertexGNN on MI355X — round 13: packed linear chunking.
// edata is dst-sorted -> chunk c = edges [16c,16c+16): exactly E/16 chunks
// (was 1.45x from per-node ceil(deg/16)). Rows carry dst (int4 payload);
// per-chunk segments found via shfl_up+ballot; masked row-sums flushed with
// 64B-aligned atomics into agg; separate k_node_update (in-place h, clears
// agg for next layer). Workspace == R12's proven 90.1MB footprint.
// ---------------------------------------------------------------------------

typedef __attribute__((ext_vector_type(8))) short bfrag;   // 8 x bf16
typedef __attribute__((ext_vector_type(4))) float ffrag;   // 4 x f32

template <int CTRL>
__device__ __forceinline__ float dpp_mov(float v) {
  return __int_as_float(
      __builtin_amdgcn_update_dpp(0, __float_as_int(v), CTRL, 0xF, 0xF, true));
}

__device__ __forceinline__ float rsum16(float v) {
  v += dpp_mov<0x128>(v);   // row_ror:8
  v += dpp_mov<0x124>(v);   // row_ror:4
  v += dpp_mov<0x122>(v);   // row_ror:2
  v += dpp_mov<0x121>(v);   // row_ror:1
  return v;
}

__device__ __forceinline__ float wave_sum64(float v) {
  v = rsum16(v);
  v += __shfl_xor(v, 16, 64);
  v += __shfl_xor(v, 32, 64);
  return v;
}

// LN with independent E[x], E[x^2] reductions (chains overlap)
__device__ __forceinline__ float ln_apply(float t, float g, float b) {
  float s1 = wave_sum64(t);
  float s2 = wave_sum64(t * t);
  float mu = s1 * 0.015625f;
  float var = fmaf(-mu, mu, s2 * 0.015625f);
  return (t - mu) * rsqrtf(var + 1e-5f) * g + b;
}

// A&S 7.1.27: erf(x) ~= 1 - 1/poly^4, |err|<=5e-4; single v_rcp.
__device__ __forceinline__ float erf_fast(float x) {
  float ax = fabsf(x);
  float p = fmaf(fmaf(fmaf(fmaf(0.078108f, ax, 0.000972f), ax, 0.230389f),
                      ax, 0.278393f), ax, 1.0f);
  p = p * p;
  p = p * p;
  float r = __builtin_amdgcn_rcpf(p);
  return copysignf(1.0f - r, x);
}

__device__ __forceinline__ float gelu_exact(float v) {
  float half = 0.5f * v;
  return fmaf(half, erf_fast(v * 0.70710678118654752440f), half);
}

__device__ __forceinline__ float lane_bcast(float v, int k) {
  return __uint_as_float(__builtin_amdgcn_readlane(__float_as_uint(v), k));
}

// float -> bf16 (RNE)
__device__ __forceinline__ short f2bf(float f) {
  union { float f; unsigned u; } v; v.f = f;
  unsigned r = v.u + 0x7fffu + ((v.u >> 16) & 1u);
  return (short)(r >> 16);
}

// ---------- merged init: prep_w | hist | embed ------------------------------
__global__ __launch_bounds__(256) void k_init(
    const float* __restrict__ x,
    const float* __restrict__ w1, const float* __restrict__ b1,
    const float* __restrict__ g1, const float* __restrict__ be1,
    const float* __restrict__ w2, const float* __restrict__ b2,
    const float* __restrict__ g2, const float* __restrict__ be2,
    const float* __restrict__ conv_w, ushort* __restrict__ wt,
    const int* __restrict__ ei, int* __restrict__ csr,
    float* __restrict__ h, ushort* __restrict__ hb,
    int n_nodes, int ne, int oHist, int oEmb, int embWaves) {
  const int bid = blockIdx.x;
  const int tid = threadIdx.x;
  if (bid < oHist) {  // prep_w: 3*64*96 = 18432 elems, 72 blocks
    const int i = bid * 256 + tid;
    const int k = i % 96, f = (i / 96) % 64, l = i / (96 * 64);
    const float v = (k < 66) ? conv_w[(size_t)l * 66 * 64 + k * 64 + f] : 0.0f;
    wt[i] = (ushort)f2bf(v);
    return;
  }
  if (bid < oEmb) {  // degree histogram (csr pre-zeroed by memsetAsync)
    const int i = (bid - oHist) * 256 + tid;
    if (i < ne) atomicAdd(&csr[ei[ne + i]], 1);
    return;
  }
  // ---- node embedding ----
  const int lane = tid & 63;
  const int wid = ((bid - oEmb) * 256 + tid) >> 6;
  const int nw = embWaves;
  float wc[64];
#pragma unroll
  for (int k = 0; k < 64; k++) wc[k] = w2[k * 64 + lane];
  const float w1a = w1[lane], w1b = w1[64 + lane];
  const float vb1 = b1[lane], vg1 = g1[lane], vbe1 = be1[lane];
  const float vb2 = b2[lane], vg2 = g2[lane], vbe2 = be2[lane];
  for (int n = wid; n < n_nodes; n += nw) {
    const float x0 = x[2 * n], x1 = x[2 * n + 1];
    float t = fmaf(x0, w1a, fmaf(x1, w1b, vb1));
    t = gelu_exact(ln_apply(t, vg1, vbe1));
    float a0 = vb2, a1 = 0.f, a2 = 0.f, a3 = 0.f;
#pragma unroll
    for (int k = 0; k < 64; k += 4) {
      a0 = fmaf(lane_bcast(t, k + 0), wc[k + 0], a0);
      a1 = fmaf(lane_bcast(t, k + 1), wc[k + 1], a1);
      a2 = fmaf(lane_bcast(t, k + 2), wc[k + 2], a2);
      a3 = fmaf(lane_bcast(t, k + 3), wc[k + 3], a3);
    }
    float acc = (a0 + a1) + (a2 + a3);
    acc = gelu_exact(ln_apply(acc, vg2, vbe2));
    h[n * 64 + lane] = acc;
    hb[n * 64 + lane] = (ushort)f2bf(acc);
  }
}

// Single-block exclusive scan, int4-vectorized chunks, ~3 barriers total.
__global__ __launch_bounds__(1024) void k_scan_fast(int* __restrict__ buf, int n) {
  __shared__ int wsum[16];
  const int tid = threadIdx.x, lane = tid & 63, w = tid >> 6;
  const int chunk = (((n + 1023) / 1024) + 3) & ~3;   // multiple of 4
  const int a = min(tid * chunk, n), b = min(a + chunk, n);
  const bool full = (a + chunk <= n);
  int s = 0;
  if (full) {
    const int4* p4 = (const int4*)(buf + a);
#pragma unroll 4
    for (int i = 0; i < chunk / 4; i++) {
      int4 v = p4[i];
      s += v.x + v.y + v.z + v.w;
    }
  } else {
    for (int i = a; i < b; i++) s += buf[i];
  }
  int inc = s;
#pragma unroll
  for (int sh = 1; sh < 64; sh <<= 1) {
    int t = __shfl_up(inc, sh, 64);
    if (lane >= sh) inc += t;
  }
  if (lane == 63) wsum[w] = inc;
  __syncthreads();
  int wb = 0;
  for (int j = 0; j < w; j++) wb += wsum[j];
  int excl = wb + inc - s;
  if (full) {
    int4* p4 = (int4*)(buf + a);
#pragma unroll 4
    for (int i = 0; i < chunk / 4; i++) {
      int4 v = p4[i];
      int4 o;
      o.x = excl; excl += v.x;
      o.y = excl; excl += v.y;
      o.z = excl; excl += v.z;
      o.w = excl; excl += v.w;
      p4[i] = o;
    }
  } else {
    for (int i = a; i < b; i++) { int v = buf[i]; buf[i] = excl; excl += v; }
  }
}

// scatter packed edge payload {src, bf16x2(ea), dst} into dst-sorted order
__global__ void k_scatter(const int* __restrict__ ei, const float* __restrict__ ea,
                          int* __restrict__ cursor, int4* __restrict__ edata, int ne) {
  int i = blockIdx.x * blockDim.x + threadIdx.x;
  if (i < ne) {
    const int d = ei[ne + i];
    const int s = ei[i];
    const float2 eav = *(const float2*)(ea + 2 * (size_t)i);
    const unsigned pk = (unsigned)(ushort)f2bf(eav.x) |
                        ((unsigned)(ushort)f2bf(eav.y) << 16);
    const int pos = atomicAdd(&cursor[d], 1);
    edata[pos] = make_int4(s, (int)pk, d, 0);
  }
}

// ---------------- packed edge-message kernel (linear chunks) ----------------
// Wave per 16-edge chunk (grid-stride). Segments (same dst) flushed with
// contiguous 64B-line atomics into agg.
__global__ __launch_bounds__(256, 3) void k_edge_packed(
    const ushort* __restrict__ hb_in, float* __restrict__ agg,
    const int4* __restrict__ edata, const ushort* __restrict__ wt,
    const float* __restrict__ bias, const float* __restrict__ mg,
    const float* __restrict__ mb, int nchunks, int ne) {
  __shared__ __align__(16) ushort lwt[64 * 96];   // 12 KB: B^T tiles
  {
    const uint4* s = (const uint4*)wt;
    uint4* d = (uint4*)lwt;
    for (int i = threadIdx.x; i < 768; i += 256) d[i] = s[i];
  }
  __syncthreads();

  const int lane = threadIdx.x & 63;
  const int grp = lane >> 4, col = lane & 15;
  const int wid = (blockIdx.x * blockDim.x + threadIdx.x) >> 6;
  const int nw = (gridDim.x * blockDim.x) >> 6;

  float vb[4], vg[4], vbb[4];
#pragma unroll
  for (int t = 0; t < 4; t++) {
    const int f = t * 16 + col;
    vb[t] = bias[f]; vg[t] = mg[f]; vbb[t] = mb[f];
  }

  int c = wid;
  if (c >= nchunks) return;
  int4 e = edata[min(16 * c + col, ne - 1)];
  {
    const ushort* hp = hb_in + (size_t)e.x * 64 + grp * 8;
    // fallthrough into loop with A0/A1 loaded
  }
  const ushort* hp0 = hb_in + (size_t)e.x * 64 + grp * 8;
  bfrag A0 = *(const bfrag*)(hp0);
  bfrag A1 = *(const bfrag*)(hp0 + 32);

  for (;;) {
    const int rem = min(16, ne - 16 * c);
    const int cn = c + nw;
    const bool more = cn < nchunks;
    const int nslot = more ? min(16 * cn + col, ne - 1) : min(16 * c + col, ne - 1);
    const int4 en = edata[nslot];   // prefetch next chunk payload

    bfrag A2 = {0, 0, 0, 0, 0, 0, 0, 0};
    if (grp == 0) {
      A2[0] = (short)(e.y & 0xffff);
      A2[1] = (short)((unsigned)e.y >> 16);
    }

    ffrag acc[4];
#pragma unroll
    for (int t = 0; t < 4; t++) { ffrag cc = {vb[t], vb[t], vb[t], vb[t]}; acc[t] = cc; }
#pragma unroll
    for (int t = 0; t < 4; t++) {
      const bfrag B = *(const bfrag*)(lwt + (t * 16 + col) * 96 + grp * 8);
      acc[t] = __builtin_amdgcn_mfma_f32_16x16x32_bf16(A0, B, acc[t], 0, 0, 0);
    }
#pragma unroll
    for (int t = 0; t < 4; t++) {
      const bfrag B = *(const bfrag*)(lwt + (t * 16 + col) * 96 + 32 + grp * 8);
      acc[t] = __builtin_amdgcn_mfma_f32_16x16x32_bf16(A1, B, acc[t], 0, 0, 0);
    }
#pragma unroll
    for (int t = 0; t < 4; t++) {
      const bfrag B = *(const bfrag*)(lwt + (t * 16 + col) * 96 + 64 + grp * 8);
      acc[t] = __builtin_amdgcn_mfma_f32_16x16x32_bf16(A2, B, acc[t], 0, 0, 0);
    }

    // prefetch next chunk's gather so it flies during the epilogue
    const ushort* hq = hb_in + (size_t)en.x * 64 + grp * 8;
    const bfrag N0 = *(const bfrag*)(hq);
    const bfrag N1 = *(const bfrag*)(hq + 32);

    // ---- per-edge LN stats via E[x] / E[x^2] (rows m = grp*4+r) ----
    float sx[4], sq[4];
#pragma unroll
    for (int r = 0; r < 4; r++) {
      float s = (acc[0][r] + acc[1][r]) + (acc[2][r] + acc[3][r]);
      float q = fmaf(acc[0][r], acc[0][r], fmaf(acc[1][r], acc[1][r],
                fmaf(acc[2][r], acc[2][r], acc[3][r] * acc[3][r])));
      sx[r] = s; sq[r] = q;
    }
#pragma unroll
    for (int r = 0; r < 4; r++) sx[r] = rsum16(sx[r]);
#pragma unroll
    for (int r = 0; r < 4; r++) sq[r] = rsum16(sq[r]);
    float iv[4], mi[4];
#pragma unroll
    for (int r = 0; r < 4; r++) {
      const float mu = sx[r] * 0.015625f;
      const float var = fmaf(-mu, mu, sq[r] * 0.015625f);
      iv[r] = rsqrtf(var + 1e-5f);
      mi[r] = -mu * iv[r];
    }

    // ---- LN-apply + GELU, in place ----
#pragma unroll
    for (int t = 0; t < 4; t++) {
#pragma unroll
      for (int r = 0; r < 4; r++) {
        const float z = fmaf(acc[t][r], iv[r], mi[r]);
        acc[t][r] = gelu_exact(fmaf(z, vg[t], vbb[t]));
      }
    }

    // ---- segment detection (dst non-decreasing within chunk) ----
    const int prev = __shfl_up(e.z, 1, 64);
    const unsigned long long bal = __ballot((col > 0) && (e.z != prev));
    const unsigned bm = (unsigned)bal & 0xFFFEu;   // boundary bits for rows 1..15

    int s0 = 0;
    while (s0 < rem) {
      const unsigned rest = bm >> (s0 + 1);
      int s1 = rest ? (s0 + 1 + __builtin_ctz(rest)) : 16;
      if (s1 > rem) s1 = rem;
      const int dseg = __builtin_amdgcn_readlane(e.z, s0);
#pragma unroll
      for (int t = 0; t < 4; t++) {
        float rs = 0.f;
#pragma unroll
        for (int r = 0; r < 4; r++) {
          const int row = grp * 4 + r;
          const float w = (row >= s0 && row < s1) ? 1.0f : 0.0f;
          rs = fmaf(acc[t][r], w, rs);
        }
        rs += __shfl_xor(rs, 16, 64);
        rs += __shfl_xor(rs, 32, 64);
        if (lane < 16)
          atomicAdd(&agg[(size_t)dseg * 64 + t * 16 + lane], rs);
      }
      s0 = s1;
    }

    if (!more) break;
    c = cn; e = en; A0 = N0; A1 = N1;
  }
}

// ---------------------- node update (in-place h) ----------------------------
// conv_out = ln(agg/deg + h); h += ln(conv_out). Clears agg for next layer.
__global__ void k_node_update(float* __restrict__ h, ushort* __restrict__ hb,
                              float* __restrict__ agg, const int* __restrict__ ends,
                              const float* __restrict__ ng, const float* __restrict__ nb,
                              const float* __restrict__ og, const float* __restrict__ ob,
                              int n_nodes, int writeHb) {
  const int lane = threadIdx.x & 63;
  const int n = (blockIdx.x * blockDim.x + threadIdx.x) >> 6;
  if (n >= n_nodes) return;
  int start, end;
  if (n == 0) { start = 0; end = ends[0]; }
  else { const int2 se = *(const int2*)(ends + n - 1); start = se.x; end = se.y; }
  const float dg = fmaxf((float)(end - start), 1.0f);
  const float hv = h[(size_t)n * 64 + lane];
  const float a = agg[(size_t)n * 64 + lane] / dg + hv;
  if (writeHb) agg[(size_t)n * 64 + lane] = 0.0f;   // re-zero for next layer
  const float c = ln_apply(a, ng[lane], nb[lane]);
  const float o = ln_apply(c, og[lane], ob[lane]);
  const float outv = hv + o;
  h[(size_t)n * 64 + lane] = outv;
  if (writeHb) hb[(size_t)n * 64 + lane] = (ushort)f2bf(outv);
}

// ------------------------------ pooling (segmented) -------------------------
__global__ void k_pool_seg(const float* __restrict__ h, const int* __restrict__ batch,
                           float* __restrict__ g, float* __restrict__ cnt,
                           int n_nodes, int chunk) {
  const int lane = threadIdx.x & 63;
  const int wid = (blockIdx.x * blockDim.x + threadIdx.x) >> 6;
  const int n0 = wid * chunk;
  if (n0 >= n_nodes) return;
  const int n1 = min(n0 + chunk, n_nodes);
  int cur = batch[n0], c = 0;
  float acc = 0.f;
  for (int n = n0; n < n1; n++) {
    const int b = batch[n];
    if (b != cur) {
      atomicAdd(&g[(size_t)cur * 64 + lane], acc);
      if (lane == 0) atomicAdd(&cnt[cur], (float)c);
      acc = 0.f; c = 0; cur = b;
    }
    acc += h[(size_t)n * 64 + lane];
    c++;
  }
  atomicAdd(&g[(size_t)cur * 64 + lane], acc);
  if (lane == 0) atomicAdd(&cnt[cur], (float)c);
}

// ------------------------------- head --------------------------------------
__global__ void k_head(const float* __restrict__ g, const float* __restrict__ cnt,
                       const float* __restrict__ w1, const float* __restrict__ b1,
                       const float* __restrict__ g1, const float* __restrict__ be1,
                       const float* __restrict__ w2, const float* __restrict__ b2,
                       const float* __restrict__ g2, const float* __restrict__ be2,
                       const float* __restrict__ w3, const float* __restrict__ b3,
                       float* __restrict__ out, int nb_) {
  const int lane = threadIdx.x & 63;
  const int row = (blockIdx.x * blockDim.x + threadIdx.x) >> 6;
  if (row >= nb_) return;
  const float c = fmaxf(cnt[row], 1.0f);
  const float gv = g[row * 64 + lane] / c;
  float a0 = b1[lane], a1 = 0.f, a2 = 0.f, a3 = 0.f;
#pragma unroll
  for (int k = 0; k < 64; k += 4) {
    a0 = fmaf(lane_bcast(gv, k + 0), w1[(k + 0) * 64 + lane], a0);
    a1 = fmaf(lane_bcast(gv, k + 1), w1[(k + 1) * 64 + lane], a1);
    a2 = fmaf(lane_bcast(gv, k + 2), w1[(k + 2) * 64 + lane], a2);
    a3 = fmaf(lane_bcast(gv, k + 3), w1[(k + 3) * 64 + lane], a3);
  }
  float t = (a0 + a1) + (a2 + a3);
  t = fmaxf(ln_apply(t, g1[lane], be1[lane]), 0.0f);

  const int j = lane & 31;
  float c0 = b2[j], c1 = 0.f, c2 = 0.f, c3 = 0.f;
#pragma unroll
  for (int k = 0; k < 64; k += 4) {
    c0 = fmaf(lane_bcast(t, k + 0), w2[(k + 0) * 32 + j], c0);
    c1 = fmaf(lane_bcast(t, k + 1), w2[(k + 1) * 32 + j], c1);
    c2 = fmaf(lane_bcast(t, k + 2), w2[(k + 2) * 32 + j], c2);
    c3 = fmaf(lane_bcast(t, k + 3), w2[(k + 3) * 32 + j], c3);
  }
  float t2 = (c0 + c1) + (c2 + c3);
  t2 = fmaxf(ln_apply(t2, g2[j], be2[j]), 0.0f);
  const float p = t2 * w3[j];
  const float s = wave_sum64(p) * 0.5f;
  if (lane == 0) out[row] = s + b3[0];
}

// ---------------------------------------------------------------------------
extern "C" void kernel_launch(void* const* d_in, const int* in_sizes, int n_in,
                              void* d_out, int out_size, void* d_ws, size_t ws_size,
                              hipStream_t stream) {
  const float* x      = (const float*)d_in[0];
  const float* ea     = (const float*)d_in[1];
  const float* ne_w1  = (const float*)d_in[2];
  const float* ne_b1  = (const float*)d_in[3];
  const float* ne_g1  = (const float*)d_in[4];
  const float* ne_be1 = (const float*)d_in[5];
  const float* ne_w2  = (const float*)d_in[6];
  const float* ne_b2  = (const float*)d_in[7];
  const float* ne_g2  = (const float*)d_in[8];
  const float* ne_be2 = (const float*)d_in[9];
  const float* conv_w = (const float*)d_in[10];
  const float* conv_b = (const float*)d_in[11];
  const float* conv_mg= (const float*)d_in[12];
  const float* conv_mb= (const float*)d_in[13];
  const float* conv_ng= (const float*)d_in[14];
  const float* conv_nb= (const float*)d_in[15];
  const float* out_ng = (const float*)d_in[16];
  const float* out_nb = (const float*)d_in[17];
  const float* m_w1   = (const float*)d_in[18];
  const float* m_b1   = (const float*)d_in[19];
  const float* m_g1   = (const float*)d_in[20];
  const float* m_be1  = (const float*)d_in[21];
  const float* m_w2   = (const float*)d_in[22];
  const float* m_b2   = (const float*)d_in[23];
  const float* m_g2   = (const float*)d_in[24];
  const float* m_be2  = (const float*)d_in[25];
  const float* m_w3   = (const float*)d_in[26];
  const float* m_b3   = (const float*)d_in[27];
  const int*   eidx   = (const int*)d_in[28];
  const int*   batch  = (const int*)d_in[29];
  float* outp = (float*)d_out;

  const int NN = in_sizes[29];
  const int NE = in_sizes[1] / 2;
  const int NB = out_size;
  const int NCH = (NE + 15) / 16;

  // workspace (== R12's proven 90.1MB footprint)
  char* wsb = (char*)d_ws;
  float*  h    = (float*)wsb;                          // NN*64 f32
  ushort* hb   = (ushort*)(h + (size_t)NN * 64);       // NN*64 bf16
  int4*   edata= (int4*)((char*)hb + ((size_t)NN * 128 + 15) / 16 * 16); // NE int4
  ushort* wt   = (ushort*)(edata + NE);                // 3*64*96 bf16
  float*  gbuf = (float*)(wt + 3 * 64 * 96);           // NB*64 f32  --+
  float*  cnt  = gbuf + (size_t)NB * 64;               // NB f32       |
  int*    csr  = (int*)(cnt + NB);                     // NN int       | one memset
  float*  agg  = (float*)((char*)(csr + NN) +          // NN*64 f32  --+
                          (((size_t)(uintptr_t)(csr + NN) & 15) ? 16 - ((size_t)(uintptr_t)(csr + NN) & 15) : 0));

  const dim3 blk(256);

  // zero gbuf + cnt + csr + agg in one contiguous memset
  const size_t zbytes = (char*)(agg + (size_t)NN * 64) - (char*)gbuf;
  hipMemsetAsync(gbuf, 0, zbytes, stream);

  // merged init: prep(72) | hist | embed(2048 blocks)
  const int nPrep = (3 * 64 * 96) / 256;              // 72
  const int nHist = (NE + 255) / 256;
  const int oHist = nPrep, oEmb = nPrep + nHist;
  const int embBlocks = 2048;
  k_init<<<oEmb + embBlocks, blk, 0, stream>>>(
      x, ne_w1, ne_b1, ne_g1, ne_be1, ne_w2, ne_b2, ne_g2, ne_be2,
      conv_w, wt, eidx, csr, h, hb, NN, NE, oHist, oEmb, embBlocks * 4);

  k_scan_fast<<<1, 1024, 0, stream>>>(csr, NN);
  k_scatter<<<(NE + 255) / 256, blk, 0, stream>>>(eidx, ea, csr, edata, NE);

  for (int l = 0; l < 3; l++) {
    k_edge_packed<<<4096, blk, 0, stream>>>(
        hb, agg, edata, wt + (size_t)l * 64 * 96,
        conv_b + l * 64, conv_mg + l * 64, conv_mb + l * 64, NCH, NE);
    k_node_update<<<(NN * 64 + 255) / 256, blk, 0, stream>>>(
        h, hb, agg, csr, conv_ng + l * 64, conv_nb + l * 64,
        out_ng + l * 64, out_nb + l * 64, NN, (l < 2) ? 1 : 0);
  }

  {
    const int chunk = 32;
    const int nwaves = (NN + chunk - 1) / chunk;
    const int nblocks = (nwaves * 64 + 255) / 256;
    k_pool_seg<<<nblocks, blk, 0, stream>>>(h, batch, gbuf, cnt, NN, chunk);
  }
  k_head<<<(NB + 3) / 4, blk, 0, stream>>>(gbuf, cnt, m_w1, m_b1, m_g1, m_be1,
                                           m_w2, m_b2, m_g2, m_be2, m_w3, m_b3,
                                           outp, NB);
}

// Round 15
// 761.367 us; speedup vs baseline: 1.2068x; 1.0064x over previous
//
#include <hip/hip_runtime.h>
#include <math.h>

// ---------------------------------------------------------------------------
// VertexGNN on MI355X — round 14 = R13 (766us best) + scatter/embed overlap.
// k_init1 = prep_w | hist;  scan;  k_combo = scatter | embed  (embed's VALU
// hides under the scatter's memory stalls — scatter is 0.6% VALUBusy).
// edata written with nontemporal stores (4x write-amplified random int4).
// ---------------------------------------------------------------------------

typedef __attribute__((ext_vector_type(8))) short bfrag;   // 8 x bf16
typedef __attribute__((ext_vector_type(4))) float ffrag;   // 4 x f32
typedef __attribute__((ext_vector_type(4))) int iv4;       // 4 x i32

template <int CTRL>
__device__ __forceinline__ float dpp_mov(float v) {
  return __int_as_float(
      __builtin_amdgcn_update_dpp(0, __float_as_int(v), CTRL, 0xF, 0xF, true));
}

__device__ __forceinline__ float rsum16(float v) {
  v += dpp_mov<0x128>(v);   // row_ror:8
  v += dpp_mov<0x124>(v);   // row_ror:4
  v += dpp_mov<0x122>(v);   // row_ror:2
  v += dpp_mov<0x121>(v);   // row_ror:1
  return v;
}

__device__ __forceinline__ float wave_sum64(float v) {
  v = rsum16(v);
  v += __shfl_xor(v, 16, 64);
  v += __shfl_xor(v, 32, 64);
  return v;
}

// LN with independent E[x], E[x^2] reductions (chains overlap)
__device__ __forceinline__ float ln_apply(float t, float g, float b) {
  float s1 = wave_sum64(t);
  float s2 = wave_sum64(t * t);
  float mu = s1 * 0.015625f;
  float var = fmaf(-mu, mu, s2 * 0.015625f);
  return (t - mu) * rsqrtf(var + 1e-5f) * g + b;
}

// A&S 7.1.27: erf(x) ~= 1 - 1/poly^4, |err|<=5e-4; single v_rcp.
__device__ __forceinline__ float erf_fast(float x) {
  float ax = fabsf(x);
  float p = fmaf(fmaf(fmaf(fmaf(0.078108f, ax, 0.000972f), ax, 0.230389f),
                      ax, 0.278393f), ax, 1.0f);
  p = p * p;
  p = p * p;
  float r = __builtin_amdgcn_rcpf(p);
  return copysignf(1.0f - r, x);
}

__device__ __forceinline__ float gelu_exact(float v) {
  float half = 0.5f * v;
  return fmaf(half, erf_fast(v * 0.70710678118654752440f), half);
}

__device__ __forceinline__ float lane_bcast(float v, int k) {
  return __uint_as_float(__builtin_amdgcn_readlane(__float_as_uint(v), k));
}

// float -> bf16 (RNE)
__device__ __forceinline__ short f2bf(float f) {
  union { float f; unsigned u; } v; v.f = f;
  unsigned r = v.u + 0x7fffu + ((v.u >> 16) & 1u);
  return (short)(r >> 16);
}

// ---------------- init stage 1: prep_w | hist -------------------------------
__global__ __launch_bounds__(256) void k_init1(
    const float* __restrict__ conv_w, ushort* __restrict__ wt,
    const int* __restrict__ ei, int* __restrict__ csr,
    int ne, int oHist) {
  const int bid = blockIdx.x;
  const int tid = threadIdx.x;
  if (bid < oHist) {  // prep_w: 3*64*96 = 18432 elems, 72 blocks
    const int i = bid * 256 + tid;
    const int k = i % 96, f = (i / 96) % 64, l = i / (96 * 64);
    const float v = (k < 66) ? conv_w[(size_t)l * 66 * 64 + k * 64 + f] : 0.0f;
    wt[i] = (ushort)f2bf(v);
    return;
  }
  const int i = (bid - oHist) * 256 + tid;   // degree histogram
  if (i < ne) atomicAdd(&csr[ei[ne + i]], 1);
}

// Single-block exclusive scan, int4-vectorized chunks, ~3 barriers total.
__global__ __launch_bounds__(1024) void k_scan_fast(int* __restrict__ buf, int n) {
  __shared__ int wsum[16];
  const int tid = threadIdx.x, lane = tid & 63, w = tid >> 6;
  const int chunk = (((n + 1023) / 1024) + 3) & ~3;   // multiple of 4
  const int a = min(tid * chunk, n), b = min(a + chunk, n);
  const bool full = (a + chunk <= n);
  int s = 0;
  if (full) {
    const int4* p4 = (const int4*)(buf + a);
#pragma unroll 4
    for (int i = 0; i < chunk / 4; i++) {
      int4 v = p4[i];
      s += v.x + v.y + v.z + v.w;
    }
  } else {
    for (int i = a; i < b; i++) s += buf[i];
  }
  int inc = s;
#pragma unroll
  for (int sh = 1; sh < 64; sh <<= 1) {
    int t = __shfl_up(inc, sh, 64);
    if (lane >= sh) inc += t;
  }
  if (lane == 63) wsum[w] = inc;
  __syncthreads();
  int wb = 0;
  for (int j = 0; j < w; j++) wb += wsum[j];
  int excl = wb + inc - s;
  if (full) {
    int4* p4 = (int4*)(buf + a);
#pragma unroll 4
    for (int i = 0; i < chunk / 4; i++) {
      int4 v = p4[i];
      int4 o;
      o.x = excl; excl += v.x;
      o.y = excl; excl += v.y;
      o.z = excl; excl += v.z;
      o.w = excl; excl += v.w;
      p4[i] = o;
    }
  } else {
    for (int i = a; i < b; i++) { int v = buf[i]; buf[i] = excl; excl += v; }
  }
}

// ---------------- init stage 2: scatter | embed -----------------------------
// scatter blocks first (long pole, memory-bound); embed rides under it.
__global__ __launch_bounds__(256) void k_combo(
    const int* __restrict__ ei, const float* __restrict__ ea,
    int* __restrict__ cursor, int4* __restrict__ edata,
    const float* __restrict__ x,
    const float* __restrict__ w1, const float* __restrict__ b1,
    const float* __restrict__ g1, const float* __restrict__ be1,
    const float* __restrict__ w2, const float* __restrict__ b2,
    const float* __restrict__ g2, const float* __restrict__ be2,
    float* __restrict__ h, ushort* __restrict__ hb,
    int n_nodes, int ne, int oEmb, int embWaves) {
  const int bid = blockIdx.x;
  const int tid = threadIdx.x;
  if (bid < oEmb) {  // ---- scatter ----
    const int i = bid * 256 + tid;
    if (i < ne) {
      const int d = ei[ne + i];
      const int s = ei[i];
      const float2 eav = *(const float2*)(ea + 2 * (size_t)i);
      const unsigned pk = (unsigned)(ushort)f2bf(eav.x) |
                          ((unsigned)(ushort)f2bf(eav.y) << 16);
      const int pos = atomicAdd(&cursor[d], 1);
      iv4 v = {s, (int)pk, d, 0};
      __builtin_nontemporal_store(v, (iv4*)(edata + pos));
    }
    return;
  }
  // ---- node embedding ----
  const int lane = tid & 63;
  const int wid = ((bid - oEmb) * 256 + tid) >> 6;
  const int nw = embWaves;
  float wc[64];
#pragma unroll
  for (int k = 0; k < 64; k++) wc[k] = w2[k * 64 + lane];
  const float w1a = w1[lane], w1b = w1[64 + lane];
  const float vb1 = b1[lane], vg1 = g1[lane], vbe1 = be1[lane];
  const float vb2 = b2[lane], vg2 = g2[lane], vbe2 = be2[lane];
  for (int n = wid; n < n_nodes; n += nw) {
    const float x0 = x[2 * n], x1 = x[2 * n + 1];
    float t = fmaf(x0, w1a, fmaf(x1, w1b, vb1));
    t = gelu_exact(ln_apply(t, vg1, vbe1));
    float a0 = vb2, a1 = 0.f, a2 = 0.f, a3 = 0.f;
#pragma unroll
    for (int k = 0; k < 64; k += 4) {
      a0 = fmaf(lane_bcast(t, k + 0), wc[k + 0], a0);
      a1 = fmaf(lane_bcast(t, k + 1), wc[k + 1], a1);
      a2 = fmaf(lane_bcast(t, k + 2), wc[k + 2], a2);
      a3 = fmaf(lane_bcast(t, k + 3), wc[k + 3], a3);
    }
    float acc = (a0 + a1) + (a2 + a3);
    acc = gelu_exact(ln_apply(acc, vg2, vbe2));
    h[n * 64 + lane] = acc;
    hb[n * 64 + lane] = (ushort)f2bf(acc);
  }
}

// ---------------- packed edge-message kernel (linear chunks) ----------------
__global__ __launch_bounds__(256, 3) void k_edge_packed(
    const ushort* __restrict__ hb_in, float* __restrict__ agg,
    const int4* __restrict__ edata, const ushort* __restrict__ wt,
    const float* __restrict__ bias, const float* __restrict__ mg,
    const float* __restrict__ mb, int nchunks, int ne) {
  __shared__ __align__(16) ushort lwt[64 * 96];   // 12 KB: B^T tiles
  {
    const uint4* s = (const uint4*)wt;
    uint4* d = (uint4*)lwt;
    for (int i = threadIdx.x; i < 768; i += 256) d[i] = s[i];
  }
  __syncthreads();

  const int lane = threadIdx.x & 63;
  const int grp = lane >> 4, col = lane & 15;
  const int wid = (blockIdx.x * blockDim.x + threadIdx.x) >> 6;
  const int nw = (gridDim.x * blockDim.x) >> 6;

  float vb[4], vg[4], vbb[4];
#pragma unroll
  for (int t = 0; t < 4; t++) {
    const int f = t * 16 + col;
    vb[t] = bias[f]; vg[t] = mg[f]; vbb[t] = mb[f];
  }

  int c = wid;
  if (c >= nchunks) return;
  int4 e = edata[min(16 * c + col, ne - 1)];
  const ushort* hp0 = hb_in + (size_t)e.x * 64 + grp * 8;
  bfrag A0 = *(const bfrag*)(hp0);
  bfrag A1 = *(const bfrag*)(hp0 + 32);

  for (;;) {
    const int rem = min(16, ne - 16 * c);
    const int cn = c + nw;
    const bool more = cn < nchunks;
    const int nslot = more ? min(16 * cn + col, ne - 1) : min(16 * c + col, ne - 1);
    const int4 en = edata[nslot];   // prefetch next chunk payload

    bfrag A2 = {0, 0, 0, 0, 0, 0, 0, 0};
    if (grp == 0) {
      A2[0] = (short)(e.y & 0xffff);
      A2[1] = (short)((unsigned)e.y >> 16);
    }

    ffrag acc[4];
#pragma unroll
    for (int t = 0; t < 4; t++) { ffrag cc = {vb[t], vb[t], vb[t], vb[t]}; acc[t] = cc; }
#pragma unroll
    for (int t = 0; t < 4; t++) {
      const bfrag B = *(const bfrag*)(lwt + (t * 16 + col) * 96 + grp * 8);
      acc[t] = __builtin_amdgcn_mfma_f32_16x16x32_bf16(A0, B, acc[t], 0, 0, 0);
    }
#pragma unroll
    for (int t = 0; t < 4; t++) {
      const bfrag B = *(const bfrag*)(lwt + (t * 16 + col) * 96 + 32 + grp * 8);
      acc[t] = __builtin_amdgcn_mfma_f32_16x16x32_bf16(A1, B, acc[t], 0, 0, 0);
    }
#pragma unroll
    for (int t = 0; t < 4; t++) {
      const bfrag B = *(const bfrag*)(lwt + (t * 16 + col) * 96 + 64 + grp * 8);
      acc[t] = __builtin_amdgcn_mfma_f32_16x16x32_bf16(A2, B, acc[t], 0, 0, 0);
    }

    // prefetch next chunk's gather so it flies during the epilogue
    const ushort* hq = hb_in + (size_t)en.x * 64 + grp * 8;
    const bfrag N0 = *(const bfrag*)(hq);
    const bfrag N1 = *(const bfrag*)(hq + 32);

    // ---- per-edge LN stats via E[x] / E[x^2] (rows m = grp*4+r) ----
    float sx[4], sq[4];
#pragma unroll
    for (int r = 0; r < 4; r++) {
      float s = (acc[0][r] + acc[1][r]) + (acc[2][r] + acc[3][r]);
      float q = fmaf(acc[0][r], acc[0][r], fmaf(acc[1][r], acc[1][r],
                fmaf(acc[2][r], acc[2][r], acc[3][r] * acc[3][r])));
      sx[r] = s; sq[r] = q;
    }
#pragma unroll
    for (int r = 0; r < 4; r++) sx[r] = rsum16(sx[r]);
#pragma unroll
    for (int r = 0; r < 4; r++) sq[r] = rsum16(sq[r]);
    float iv[4], mi[4];
#pragma unroll
    for (int r = 0; r < 4; r++) {
      const float mu = sx[r] * 0.015625f;
      const float var = fmaf(-mu, mu, sq[r] * 0.015625f);
      iv[r] = rsqrtf(var + 1e-5f);
      mi[r] = -mu * iv[r];
    }

    // ---- LN-apply + GELU, in place ----
#pragma unroll
    for (int t = 0; t < 4; t++) {
#pragma unroll
      for (int r = 0; r < 4; r++) {
        const float z = fmaf(acc[t][r], iv[r], mi[r]);
        acc[t][r] = gelu_exact(fmaf(z, vg[t], vbb[t]));
      }
    }

    // ---- segment detection (dst non-decreasing within chunk) ----
    const int prev = __shfl_up(e.z, 1, 64);
    const unsigned long long bal = __ballot((col > 0) && (e.z != prev));
    const unsigned bm = (unsigned)bal & 0xFFFEu;   // boundary bits rows 1..15

    int s0 = 0;
    while (s0 < rem) {
      const unsigned rest = bm >> (s0 + 1);
      int s1 = rest ? (s0 + 1 + __builtin_ctz(rest)) : 16;
      if (s1 > rem) s1 = rem;
      const int dseg = __builtin_amdgcn_readlane(e.z, s0);
#pragma unroll
      for (int t = 0; t < 4; t++) {
        float rs = 0.f;
#pragma unroll
        for (int r = 0; r < 4; r++) {
          const int row = grp * 4 + r;
          const float w = (row >= s0 && row < s1) ? 1.0f : 0.0f;
          rs = fmaf(acc[t][r], w, rs);
        }
        rs += __shfl_xor(rs, 16, 64);
        rs += __shfl_xor(rs, 32, 64);
        if (lane < 16)
          atomicAdd(&agg[(size_t)dseg * 64 + t * 16 + lane], rs);
      }
      s0 = s1;
    }

    if (!more) break;
    c = cn; e = en; A0 = N0; A1 = N1;
  }
}

// ---------------------- node update (in-place h) ----------------------------
__global__ void k_node_update(float* __restrict__ h, ushort* __restrict__ hb,
                              float* __restrict__ agg, const int* __restrict__ ends,
                              const float* __restrict__ ng, const float* __restrict__ nb,
                              const float* __restrict__ og, const float* __restrict__ ob,
                              int n_nodes, int writeHb) {
  const int lane = threadIdx.x & 63;
  const int n = (blockIdx.x * blockDim.x + threadIdx.x) >> 6;
  if (n >= n_nodes) return;
  int start, end;
  if (n == 0) { start = 0; end = ends[0]; }
  else { const int2 se = *(const int2*)(ends + n - 1); start = se.x; end = se.y; }
  const float dg = fmaxf((float)(end - start), 1.0f);
  const float hv = h[(size_t)n * 64 + lane];
  const float a = agg[(size_t)n * 64 + lane] / dg + hv;
  if (writeHb) agg[(size_t)n * 64 + lane] = 0.0f;   // re-zero for next layer
  const float c = ln_apply(a, ng[lane], nb[lane]);
  const float o = ln_apply(c, og[lane], ob[lane]);
  const float outv = hv + o;
  h[(size_t)n * 64 + lane] = outv;
  if (writeHb) hb[(size_t)n * 64 + lane] = (ushort)f2bf(outv);
}

// ------------------------------ pooling (segmented) -------------------------
__global__ void k_pool_seg(const float* __restrict__ h, const int* __restrict__ batch,
                           float* __restrict__ g, float* __restrict__ cnt,
                           int n_nodes, int chunk) {
  const int lane = threadIdx.x & 63;
  const int wid = (blockIdx.x * blockDim.x + threadIdx.x) >> 6;
  const int n0 = wid * chunk;
  if (n0 >= n_nodes) return;
  const int n1 = min(n0 + chunk, n_nodes);
  int cur = batch[n0], c = 0;
  float acc = 0.f;
  for (int n = n0; n < n1; n++) {
    const int b = batch[n];
    if (b != cur) {
      atomicAdd(&g[(size_t)cur * 64 + lane], acc);
      if (lane == 0) atomicAdd(&cnt[cur], (float)c);
      acc = 0.f; c = 0; cur = b;
    }
    acc += h[(size_t)n * 64 + lane];
    c++;
  }
  atomicAdd(&g[(size_t)cur * 64 + lane], acc);
  if (lane == 0) atomicAdd(&cnt[cur], (float)c);
}

// ------------------------------- head --------------------------------------
__global__ void k_head(const float* __restrict__ g, const float* __restrict__ cnt,
                       const float* __restrict__ w1, const float* __restrict__ b1,
                       const float* __restrict__ g1, const float* __restrict__ be1,
                       const float* __restrict__ w2, const float* __restrict__ b2,
                       const float* __restrict__ g2, const float* __restrict__ be2,
                       const float* __restrict__ w3, const float* __restrict__ b3,
                       float* __restrict__ out, int nb_) {
  const int lane = threadIdx.x & 63;
  const int row = (blockIdx.x * blockDim.x + threadIdx.x) >> 6;
  if (row >= nb_) return;
  const float c = fmaxf(cnt[row], 1.0f);
  const float gv = g[row * 64 + lane] / c;
  float a0 = b1[lane], a1 = 0.f, a2 = 0.f, a3 = 0.f;
#pragma unroll
  for (int k = 0; k < 64; k += 4) {
    a0 = fmaf(lane_bcast(gv, k + 0), w1[(k + 0) * 64 + lane], a0);
    a1 = fmaf(lane_bcast(gv, k + 1), w1[(k + 1) * 64 + lane], a1);
    a2 = fmaf(lane_bcast(gv, k + 2), w1[(k + 2) * 64 + lane], a2);
    a3 = fmaf(lane_bcast(gv, k + 3), w1[(k + 3) * 64 + lane], a3);
  }
  float t = (a0 + a1) + (a2 + a3);
  t = fmaxf(ln_apply(t, g1[lane], be1[lane]), 0.0f);

  const int j = lane & 31;
  float c0 = b2[j], c1 = 0.f, c2 = 0.f, c3 = 0.f;
#pragma unroll
  for (int k = 0; k < 64; k += 4) {
    c0 = fmaf(lane_bcast(t, k + 0), w2[(k + 0) * 32 + j], c0);
    c1 = fmaf(lane_bcast(t, k + 1), w2[(k + 1) * 32 + j], c1);
    c2 = fmaf(lane_bcast(t, k + 2), w2[(k + 2) * 32 + j], c2);
    c3 = fmaf(lane_bcast(t, k + 3), w2[(k + 3) * 32 + j], c3);
  }
  float t2 = (c0 + c1) + (c2 + c3);
  t2 = fmaxf(ln_apply(t2, g2[j], be2[j]), 0.0f);
  const float p = t2 * w3[j];
  const float s = wave_sum64(p) * 0.5f;
  if (lane == 0) out[row] = s + b3[0];
}

// ---------------------------------------------------------------------------
extern "C" void kernel_launch(void* const* d_in, const int* in_sizes, int n_in,
                              void* d_out, int out_size, void* d_ws, size_t ws_size,
                              hipStream_t stream) {
  const float* x      = (const float*)d_in[0];
  const float* ea     = (const float*)d_in[1];
  const float* ne_w1  = (const float*)d_in[2];
  const float* ne_b1  = (const float*)d_in[3];
  const float* ne_g1  = (const float*)d_in[4];
  const float* ne_be1 = (const float*)d_in[5];
  const float* ne_w2  = (const float*)d_in[6];
  const float* ne_b2  = (const float*)d_in[7];
  const float* ne_g2  = (const float*)d_in[8];
  const float* ne_be2 = (const float*)d_in[9];
  const float* conv_w = (const float*)d_in[10];
  const float* conv_b = (const float*)d_in[11];
  const float* conv_mg= (const float*)d_in[12];
  const float* conv_mb= (const float*)d_in[13];
  const float* conv_ng= (const float*)d_in[14];
  const float* conv_nb= (const float*)d_in[15];
  const float* out_ng = (const float*)d_in[16];
  const float* out_nb = (const float*)d_in[17];
  const float* m_w1   = (const float*)d_in[18];
  const float* m_b1   = (const float*)d_in[19];
  const float* m_g1   = (const float*)d_in[20];
  const float* m_be1  = (const float*)d_in[21];
  const float* m_w2   = (const float*)d_in[22];
  const float* m_b2   = (const float*)d_in[23];
  const float* m_g2   = (const float*)d_in[24];
  const float* m_be2  = (const float*)d_in[25];
  const float* m_w3   = (const float*)d_in[26];
  const float* m_b3   = (const float*)d_in[27];
  const int*   eidx   = (const int*)d_in[28];
  const int*   batch  = (const int*)d_in[29];
  float* outp = (float*)d_out;

  const int NN = in_sizes[29];
  const int NE = in_sizes[1] / 2;
  const int NB = out_size;
  const int NCH = (NE + 15) / 16;

  // workspace (== R13's proven footprint)
  char* wsb = (char*)d_ws;
  float*  h    = (float*)wsb;                          // NN*64 f32
  ushort* hb   = (ushort*)(h + (size_t)NN * 64);       // NN*64 bf16
  int4*   edata= (int4*)((char*)hb + ((size_t)NN * 128 + 15) / 16 * 16); // NE int4
  ushort* wt   = (ushort*)(edata + NE);                // 3*64*96 bf16
  float*  gbuf = (float*)(wt + 3 * 64 * 96);           // NB*64 f32  --+
  float*  cnt  = gbuf + (size_t)NB * 64;               // NB f32       |
  int*    csr  = (int*)(cnt + NB);                     // NN int       | one memset
  float*  agg  = (float*)((char*)(csr + NN) +          // NN*64 f32  --+
                          (((size_t)(uintptr_t)(csr + NN) & 15) ? 16 - ((size_t)(uintptr_t)(csr + NN) & 15) : 0));

  const dim3 blk(256);

  // zero gbuf + cnt + csr + agg in one contiguous memset
  const size_t zbytes = (char*)(agg + (size_t)NN * 64) - (char*)gbuf;
  hipMemsetAsync(gbuf, 0, zbytes, stream);

  // stage 1: prep(72) | hist
  const int nPrep = (3 * 64 * 96) / 256;              // 72
  const int nHist = (NE + 255) / 256;
  k_init1<<<nPrep + nHist, blk, 0, stream>>>(conv_w, wt, eidx, csr, NE, nPrep);

  k_scan_fast<<<1, 1024, 0, stream>>>(csr, NN);

  // stage 2: scatter | embed (scatter first — long pole)
  const int nScat = (NE + 255) / 256;
  const int embBlocks = 2048;
  k_combo<<<nScat + embBlocks, blk, 0, stream>>>(
      eidx, ea, csr, edata, x,
      ne_w1, ne_b1, ne_g1, ne_be1, ne_w2, ne_b2, ne_g2, ne_be2,
      h, hb, NN, NE, nScat, embBlocks * 4);

  for (int l = 0; l < 3; l++) {
    k_edge_packed<<<4096, blk, 0, stream>>>(
        hb, agg, edata, wt + (size_t)l * 64 * 96,
        conv_b + l * 64, conv_mg + l * 64, conv_mb + l * 64, NCH, NE);
    k_node_update<<<(NN * 64 + 255) / 256, blk, 0, stream>>>(
        h, hb, agg, csr, conv_ng + l * 64, conv_nb + l * 64,
        out_ng + l * 64, out_nb + l * 64, NN, (l < 2) ? 1 : 0);
  }

  {
    const int chunk = 32;
    const int nwaves = (NN + chunk - 1) / chunk;
    const int nblocks = (nwaves * 64 + 255) / 256;
    k_pool_seg<<<nblocks, blk, 0, stream>>>(h, batch, gbuf, cnt, NN, chunk);
  }
  k_head<<<(NB + 3) / 4, blk, 0, stream>>>(gbuf, cnt, m_w1, m_b1, m_g1, m_be1,
                                           m_w2, m_b2, m_g2, m_be2, m_w3, m_b3,
                                           outp, NB);
}

// Round 16
// 731.236 us; speedup vs baseline: 1.2566x; 1.0412x over previous
//
#include <hip/hip_runtime.h>
#include <math.h>

// ---------------------------------------------------------------------------
// VertexGNN on MI355X — round 15 = R14 + XCD-partitioned scatter.
// Scatter writes are the pole (random int4, ~4x line amplification, no L2
// merge because a line's writers span XCDs). Fix: role = bid&7 (~XCD under
// round-robin dispatch); role r claims only dst-range r -> every edata line
// written by ONE XCD -> L2 merges -> writeback ~25.6MB clean. dst scanned 8x
// (L2/L3 reads, cheap). Embed interleaved: blocks 24..31 of each 32-group.
// ---------------------------------------------------------------------------

typedef __attribute__((ext_vector_type(8))) short bfrag;   // 8 x bf16
typedef __attribute__((ext_vector_type(4))) float ffrag;   // 4 x f32

template <int CTRL>
__device__ __forceinline__ float dpp_mov(float v) {
  return __int_as_float(
      __builtin_amdgcn_update_dpp(0, __float_as_int(v), CTRL, 0xF, 0xF, true));
}

__device__ __forceinline__ float rsum16(float v) {
  v += dpp_mov<0x128>(v);   // row_ror:8
  v += dpp_mov<0x124>(v);   // row_ror:4
  v += dpp_mov<0x122>(v);   // row_ror:2
  v += dpp_mov<0x121>(v);   // row_ror:1
  return v;
}

__device__ __forceinline__ float wave_sum64(float v) {
  v = rsum16(v);
  v += __shfl_xor(v, 16, 64);
  v += __shfl_xor(v, 32, 64);
  return v;
}

// LN with independent E[x], E[x^2] reductions (chains overlap)
__device__ __forceinline__ float ln_apply(float t, float g, float b) {
  float s1 = wave_sum64(t);
  float s2 = wave_sum64(t * t);
  float mu = s1 * 0.015625f;
  float var = fmaf(-mu, mu, s2 * 0.015625f);
  return (t - mu) * rsqrtf(var + 1e-5f) * g + b;
}

// A&S 7.1.27: erf(x) ~= 1 - 1/poly^4, |err|<=5e-4; single v_rcp.
__device__ __forceinline__ float erf_fast(float x) {
  float ax = fabsf(x);
  float p = fmaf(fmaf(fmaf(fmaf(0.078108f, ax, 0.000972f), ax, 0.230389f),
                      ax, 0.278393f), ax, 1.0f);
  p = p * p;
  p = p * p;
  float r = __builtin_amdgcn_rcpf(p);
  return copysignf(1.0f - r, x);
}

__device__ __forceinline__ float gelu_exact(float v) {
  float half = 0.5f * v;
  return fmaf(half, erf_fast(v * 0.70710678118654752440f), half);
}

__device__ __forceinline__ float lane_bcast(float v, int k) {
  return __uint_as_float(__builtin_amdgcn_readlane(__float_as_uint(v), k));
}

// float -> bf16 (RNE)
__device__ __forceinline__ short f2bf(float f) {
  union { float f; unsigned u; } v; v.f = f;
  unsigned r = v.u + 0x7fffu + ((v.u >> 16) & 1u);
  return (short)(r >> 16);
}

// ---------------- init stage 1: prep_w | hist -------------------------------
__global__ __launch_bounds__(256) void k_init1(
    const float* __restrict__ conv_w, ushort* __restrict__ wt,
    const int* __restrict__ ei, int* __restrict__ csr,
    int ne, int oHist) {
  const int bid = blockIdx.x;
  const int tid = threadIdx.x;
  if (bid < oHist) {  // prep_w: 3*64*96 = 18432 elems, 72 blocks
    const int i = bid * 256 + tid;
    const int k = i % 96, f = (i / 96) % 64, l = i / (96 * 64);
    const float v = (k < 66) ? conv_w[(size_t)l * 66 * 64 + k * 64 + f] : 0.0f;
    wt[i] = (ushort)f2bf(v);
    return;
  }
  const int i = (bid - oHist) * 256 + tid;   // degree histogram
  if (i < ne) atomicAdd(&csr[ei[ne + i]], 1);
}

// Single-block exclusive scan, int4-vectorized chunks, ~3 barriers total.
__global__ __launch_bounds__(1024) void k_scan_fast(int* __restrict__ buf, int n) {
  __shared__ int wsum[16];
  const int tid = threadIdx.x, lane = tid & 63, w = tid >> 6;
  const int chunk = (((n + 1023) / 1024) + 3) & ~3;   // multiple of 4
  const int a = min(tid * chunk, n), b = min(a + chunk, n);
  const bool full = (a + chunk <= n);
  int s = 0;
  if (full) {
    const int4* p4 = (const int4*)(buf + a);
#pragma unroll 4
    for (int i = 0; i < chunk / 4; i++) {
      int4 v = p4[i];
      s += v.x + v.y + v.z + v.w;
    }
  } else {
    for (int i = a; i < b; i++) s += buf[i];
  }
  int inc = s;
#pragma unroll
  for (int sh = 1; sh < 64; sh <<= 1) {
    int t = __shfl_up(inc, sh, 64);
    if (lane >= sh) inc += t;
  }
  if (lane == 63) wsum[w] = inc;
  __syncthreads();
  int wb = 0;
  for (int j = 0; j < w; j++) wb += wsum[j];
  int excl = wb + inc - s;
  if (full) {
    int4* p4 = (int4*)(buf + a);
#pragma unroll 4
    for (int i = 0; i < chunk / 4; i++) {
      int4 v = p4[i];
      int4 o;
      o.x = excl; excl += v.x;
      o.y = excl; excl += v.y;
      o.z = excl; excl += v.z;
      o.w = excl; excl += v.w;
      p4[i] = o;
    }
  } else {
    for (int i = a; i < b; i++) { int v = buf[i]; buf[i] = excl; excl += v; }
  }
}

// ---------------- init stage 2: XCD-partitioned scatter | embed -------------
// Per 32-block group: blocks 0..23 scatter (role = bid&7 ~ XCD; claims only
// dst-range `role`), blocks 24..31 embed. nOrd = 3*ngroups ordinals per role.
__global__ __launch_bounds__(256) void k_combo(
    const int* __restrict__ ei, const float* __restrict__ ea,
    int* __restrict__ cursor, int4* __restrict__ edata,
    const float* __restrict__ x,
    const float* __restrict__ w1, const float* __restrict__ b1,
    const float* __restrict__ g1, const float* __restrict__ be1,
    const float* __restrict__ w2, const float* __restrict__ b2,
    const float* __restrict__ g2, const float* __restrict__ be2,
    float* __restrict__ h, ushort* __restrict__ hb,
    int n_nodes, int ne, int nOrd, int embWaves, float roleScale) {
  const int bid = blockIdx.x;
  const int tid = threadIdx.x;
  const int sub = bid & 31;
  if (sub < 24) {  // ---- scatter (role-partitioned) ----
    const int role = bid & 7;
    const int ord = (bid >> 5) * 3 + (sub >> 3);     // ordinal within role
    const int lo = (int)((long long)ord * ne / nOrd);
    const int hi = (int)((long long)(ord + 1) * ne / nOrd);
    for (int i = lo + tid; i < hi; i += 256) {
      const int d = ei[ne + i];
      const int rd = min(7, (int)((float)d * roleScale));
      if (rd == role) {
        const int s = ei[i];
        const float2 eav = *(const float2*)(ea + 2 * (size_t)i);
        const unsigned pk = (unsigned)(ushort)f2bf(eav.x) |
                            ((unsigned)(ushort)f2bf(eav.y) << 16);
        const int pos = atomicAdd(&cursor[d], 1);
        edata[pos] = make_int4(s, (int)pk, d, 0);
      }
    }
    return;
  }
  // ---- node embedding ----
  const int lane = tid & 63;
  const int eblk = (bid >> 5) * 8 + (sub - 24);
  const int wid = (eblk * 256 + tid) >> 6;
  const int nw = embWaves;
  float wc[64];
#pragma unroll
  for (int k = 0; k < 64; k++) wc[k] = w2[k * 64 + lane];
  const float w1a = w1[lane], w1b = w1[64 + lane];
  const float vb1 = b1[lane], vg1 = g1[lane], vbe1 = be1[lane];
  const float vb2 = b2[lane], vg2 = g2[lane], vbe2 = be2[lane];
  for (int n = wid; n < n_nodes; n += nw) {
    const float x0 = x[2 * n], x1 = x[2 * n + 1];
    float t = fmaf(x0, w1a, fmaf(x1, w1b, vb1));
    t = gelu_exact(ln_apply(t, vg1, vbe1));
    float a0 = vb2, a1 = 0.f, a2 = 0.f, a3 = 0.f;
#pragma unroll
    for (int k = 0; k < 64; k += 4) {
      a0 = fmaf(lane_bcast(t, k + 0), wc[k + 0], a0);
      a1 = fmaf(lane_bcast(t, k + 1), wc[k + 1], a1);
      a2 = fmaf(lane_bcast(t, k + 2), wc[k + 2], a2);
      a3 = fmaf(lane_bcast(t, k + 3), wc[k + 3], a3);
    }
    float acc = (a0 + a1) + (a2 + a3);
    acc = gelu_exact(ln_apply(acc, vg2, vbe2));
    h[n * 64 + lane] = acc;
    hb[n * 64 + lane] = (ushort)f2bf(acc);
  }
}

// ---------------- packed edge-message kernel (linear chunks) ----------------
__global__ __launch_bounds__(256, 3) void k_edge_packed(
    const ushort* __restrict__ hb_in, float* __restrict__ agg,
    const int4* __restrict__ edata, const ushort* __restrict__ wt,
    const float* __restrict__ bias, const float* __restrict__ mg,
    const float* __restrict__ mb, int nchunks, int ne) {
  __shared__ __align__(16) ushort lwt[64 * 96];   // 12 KB: B^T tiles
  {
    const uint4* s = (const uint4*)wt;
    uint4* d = (uint4*)lwt;
    for (int i = threadIdx.x; i < 768; i += 256) d[i] = s[i];
  }
  __syncthreads();

  const int lane = threadIdx.x & 63;
  const int grp = lane >> 4, col = lane & 15;
  const int wid = (blockIdx.x * blockDim.x + threadIdx.x) >> 6;
  const int nw = (gridDim.x * blockDim.x) >> 6;

  float vb[4], vg[4], vbb[4];
#pragma unroll
  for (int t = 0; t < 4; t++) {
    const int f = t * 16 + col;
    vb[t] = bias[f]; vg[t] = mg[f]; vbb[t] = mb[f];
  }

  int c = wid;
  if (c >= nchunks) return;
  int4 e = edata[min(16 * c + col, ne - 1)];
  const ushort* hp0 = hb_in + (size_t)e.x * 64 + grp * 8;
  bfrag A0 = *(const bfrag*)(hp0);
  bfrag A1 = *(const bfrag*)(hp0 + 32);

  for (;;) {
    const int rem = min(16, ne - 16 * c);
    const int cn = c + nw;
    const bool more = cn < nchunks;
    const int nslot = more ? min(16 * cn + col, ne - 1) : min(16 * c + col, ne - 1);
    const int4 en = edata[nslot];   // prefetch next chunk payload

    bfrag A2 = {0, 0, 0, 0, 0, 0, 0, 0};
    if (grp == 0) {
      A2[0] = (short)(e.y & 0xffff);
      A2[1] = (short)((unsigned)e.y >> 16);
    }

    ffrag acc[4];
#pragma unroll
    for (int t = 0; t < 4; t++) { ffrag cc = {vb[t], vb[t], vb[t], vb[t]}; acc[t] = cc; }
#pragma unroll
    for (int t = 0; t < 4; t++) {
      const bfrag B = *(const bfrag*)(lwt + (t * 16 + col) * 96 + grp * 8);
      acc[t] = __builtin_amdgcn_mfma_f32_16x16x32_bf16(A0, B, acc[t], 0, 0, 0);
    }
#pragma unroll
    for (int t = 0; t < 4; t++) {
      const bfrag B = *(const bfrag*)(lwt + (t * 16 + col) * 96 + 32 + grp * 8);
      acc[t] = __builtin_amdgcn_mfma_f32_16x16x32_bf16(A1, B, acc[t], 0, 0, 0);
    }
#pragma unroll
    for (int t = 0; t < 4; t++) {
      const bfrag B = *(const bfrag*)(lwt + (t * 16 + col) * 96 + 64 + grp * 8);
      acc[t] = __builtin_amdgcn_mfma_f32_16x16x32_bf16(A2, B, acc[t], 0, 0, 0);
    }

    // prefetch next chunk's gather so it flies during the epilogue
    const ushort* hq = hb_in + (size_t)en.x * 64 + grp * 8;
    const bfrag N0 = *(const bfrag*)(hq);
    const bfrag N1 = *(const bfrag*)(hq + 32);

    // ---- per-edge LN stats via E[x] / E[x^2] (rows m = grp*4+r) ----
    float sx[4], sq[4];
#pragma unroll
    for (int r = 0; r < 4; r++) {
      float s = (acc[0][r] + acc[1][r]) + (acc[2][r] + acc[3][r]);
      float q = fmaf(acc[0][r], acc[0][r], fmaf(acc[1][r], acc[1][r],
                fmaf(acc[2][r], acc[2][r], acc[3][r] * acc[3][r])));
      sx[r] = s; sq[r] = q;
    }
#pragma unroll
    for (int r = 0; r < 4; r++) sx[r] = rsum16(sx[r]);
#pragma unroll
    for (int r = 0; r < 4; r++) sq[r] = rsum16(sq[r]);
    float iv[4], mi[4];
#pragma unroll
    for (int r = 0; r < 4; r++) {
      const float mu = sx[r] * 0.015625f;
      const float var = fmaf(-mu, mu, sq[r] * 0.015625f);
      iv[r] = rsqrtf(var + 1e-5f);
      mi[r] = -mu * iv[r];
    }

    // ---- LN-apply + GELU, in place ----
#pragma unroll
    for (int t = 0; t < 4; t++) {
#pragma unroll
      for (int r = 0; r < 4; r++) {
        const float z = fmaf(acc[t][r], iv[r], mi[r]);
        acc[t][r] = gelu_exact(fmaf(z, vg[t], vbb[t]));
      }
    }

    // ---- segment detection (dst non-decreasing within chunk) ----
    const int prev = __shfl_up(e.z, 1, 64);
    const unsigned long long bal = __ballot((col > 0) && (e.z != prev));
    const unsigned bm = (unsigned)bal & 0xFFFEu;   // boundary bits rows 1..15

    int s0 = 0;
    while (s0 < rem) {
      const unsigned rest = bm >> (s0 + 1);
      int s1 = rest ? (s0 + 1 + __builtin_ctz(rest)) : 16;
      if (s1 > rem) s1 = rem;
      const int dseg = __builtin_amdgcn_readlane(e.z, s0);
#pragma unroll
      for (int t = 0; t < 4; t++) {
        float rs = 0.f;
#pragma unroll
        for (int r = 0; r < 4; r++) {
          const int row = grp * 4 + r;
          const float w = (row >= s0 && row < s1) ? 1.0f : 0.0f;
          rs = fmaf(acc[t][r], w, rs);
        }
        rs += __shfl_xor(rs, 16, 64);
        rs += __shfl_xor(rs, 32, 64);
        if (lane < 16)
          atomicAdd(&agg[(size_t)dseg * 64 + t * 16 + lane], rs);
      }
      s0 = s1;
    }

    if (!more) break;
    c = cn; e = en; A0 = N0; A1 = N1;
  }
}

// ---------------------- node update (in-place h) ----------------------------
__global__ void k_node_update(float* __restrict__ h, ushort* __restrict__ hb,
                              float* __restrict__ agg, const int* __restrict__ ends,
                              const float* __restrict__ ng, const float* __restrict__ nb,
                              const float* __restrict__ og, const float* __restrict__ ob,
                              int n_nodes, int writeHb) {
  const int lane = threadIdx.x & 63;
  const int n = (blockIdx.x * blockDim.x + threadIdx.x) >> 6;
  if (n >= n_nodes) return;
  int start, end;
  if (n == 0) { start = 0; end = ends[0]; }
  else { const int2 se = *(const int2*)(ends + n - 1); start = se.x; end = se.y; }
  const float dg = fmaxf((float)(end - start), 1.0f);
  const float hv = h[(size_t)n * 64 + lane];
  const float a = agg[(size_t)n * 64 + lane] / dg + hv;
  if (writeHb) agg[(size_t)n * 64 + lane] = 0.0f;   // re-zero for next layer
  const float c = ln_apply(a, ng[lane], nb[lane]);
  const float o = ln_apply(c, og[lane], ob[lane]);
  const float outv = hv + o;
  h[(size_t)n * 64 + lane] = outv;
  if (writeHb) hb[(size_t)n * 64 + lane] = (ushort)f2bf(outv);
}

// ------------------------------ pooling (segmented) -------------------------
__global__ void k_pool_seg(const float* __restrict__ h, const int* __restrict__ batch,
                           float* __restrict__ g, float* __restrict__ cnt,
                           int n_nodes, int chunk) {
  const int lane = threadIdx.x & 63;
  const int wid = (blockIdx.x * blockDim.x + threadIdx.x) >> 6;
  const int n0 = wid * chunk;
  if (n0 >= n_nodes) return;
  const int n1 = min(n0 + chunk, n_nodes);
  int cur = batch[n0], c = 0;
  float acc = 0.f;
  for (int n = n0; n < n1; n++) {
    const int b = batch[n];
    if (b != cur) {
      atomicAdd(&g[(size_t)cur * 64 + lane], acc);
      if (lane == 0) atomicAdd(&cnt[cur], (float)c);
      acc = 0.f; c = 0; cur = b;
    }
    acc += h[(size_t)n * 64 + lane];
    c++;
  }
  atomicAdd(&g[(size_t)cur * 64 + lane], acc);
  if (lane == 0) atomicAdd(&cnt[cur], (float)c);
}

// ------------------------------- head --------------------------------------
__global__ void k_head(const float* __restrict__ g, const float* __restrict__ cnt,
                       const float* __restrict__ w1, const float* __restrict__ b1,
                       const float* __restrict__ g1, const float* __restrict__ be1,
                       const float* __restrict__ w2, const float* __restrict__ b2,
                       const float* __restrict__ g2, const float* __restrict__ be2,
                       const float* __restrict__ w3, const float* __restrict__ b3,
                       float* __restrict__ out, int nb_) {
  const int lane = threadIdx.x & 63;
  const int row = (blockIdx.x * blockDim.x + threadIdx.x) >> 6;
  if (row >= nb_) return;
  const float c = fmaxf(cnt[row], 1.0f);
  const float gv = g[row * 64 + lane] / c;
  float a0 = b1[lane], a1 = 0.f, a2 = 0.f, a3 = 0.f;
#pragma unroll
  for (int k = 0; k < 64; k += 4) {
    a0 = fmaf(lane_bcast(gv, k + 0), w1[(k + 0) * 64 + lane], a0);
    a1 = fmaf(lane_bcast(gv, k + 1), w1[(k + 1) * 64 + lane], a1);
    a2 = fmaf(lane_bcast(gv, k + 2), w1[(k + 2) * 64 + lane], a2);
    a3 = fmaf(lane_bcast(gv, k + 3), w1[(k + 3) * 64 + lane], a3);
  }
  float t = (a0 + a1) + (a2 + a3);
  t = fmaxf(ln_apply(t, g1[lane], be1[lane]), 0.0f);

  const int j = lane & 31;
  float c0 = b2[j], c1 = 0.f, c2 = 0.f, c3 = 0.f;
#pragma unroll
  for (int k = 0; k < 64; k += 4) {
    c0 = fmaf(lane_bcast(t, k + 0), w2[(k + 0) * 32 + j], c0);
    c1 = fmaf(lane_bcast(t, k + 1), w2[(k + 1) * 32 + j], c1);
    c2 = fmaf(lane_bcast(t, k + 2), w2[(k + 2) * 32 + j], c2);
    c3 = fmaf(lane_bcast(t, k + 3), w2[(k + 3) * 32 + j], c3);
  }
  float t2 = (c0 + c1) + (c2 + c3);
  t2 = fmaxf(ln_apply(t2, g2[j], be2[j]), 0.0f);
  const float p = t2 * w3[j];
  const float s = wave_sum64(p) * 0.5f;
  if (lane == 0) out[row] = s + b3[0];
}

// ---------------------------------------------------------------------------
extern "C" void kernel_launch(void* const* d_in, const int* in_sizes, int n_in,
                              void* d_out, int out_size, void* d_ws, size_t ws_size,
                              hipStream_t stream) {
  const float* x      = (const float*)d_in[0];
  const float* ea     = (const float*)d_in[1];
  const float* ne_w1  = (const float*)d_in[2];
  const float* ne_b1  = (const float*)d_in[3];
  const float* ne_g1  = (const float*)d_in[4];
  const float* ne_be1 = (const float*)d_in[5];
  const float* ne_w2  = (const float*)d_in[6];
  const float* ne_b2  = (const float*)d_in[7];
  const float* ne_g2  = (const float*)d_in[8];
  const float* ne_be2 = (const float*)d_in[9];
  const float* conv_w = (const float*)d_in[10];
  const float* conv_b = (const float*)d_in[11];
  const float* conv_mg= (const float*)d_in[12];
  const float* conv_mb= (const float*)d_in[13];
  const float* conv_ng= (const float*)d_in[14];
  const float* conv_nb= (const float*)d_in[15];
  const float* out_ng = (const float*)d_in[16];
  const float* out_nb = (const float*)d_in[17];
  const float* m_w1   = (const float*)d_in[18];
  const float* m_b1   = (const float*)d_in[19];
  const float* m_g1   = (const float*)d_in[20];
  const float* m_be1  = (const float*)d_in[21];
  const float* m_w2   = (const float*)d_in[22];
  const float* m_b2   = (const float*)d_in[23];
  const float* m_g2   = (const float*)d_in[24];
  const float* m_be2  = (const float*)d_in[25];
  const float* m_w3   = (const float*)d_in[26];
  const float* m_b3   = (const float*)d_in[27];
  const int*   eidx   = (const int*)d_in[28];
  const int*   batch  = (const int*)d_in[29];
  float* outp = (float*)d_out;

  const int NN = in_sizes[29];
  const int NE = in_sizes[1] / 2;
  const int NB = out_size;
  const int NCH = (NE + 15) / 16;

  // workspace (== R13's proven footprint)
  char* wsb = (char*)d_ws;
  float*  h    = (float*)wsb;                          // NN*64 f32
  ushort* hb   = (ushort*)(h + (size_t)NN * 64);       // NN*64 bf16
  int4*   edata= (int4*)((char*)hb + ((size_t)NN * 128 + 15) / 16 * 16); // NE int4
  ushort* wt   = (ushort*)(edata + NE);                // 3*64*96 bf16
  float*  gbuf = (float*)(wt + 3 * 64 * 96);           // NB*64 f32  --+
  float*  cnt  = gbuf + (size_t)NB * 64;               // NB f32       |
  int*    csr  = (int*)(cnt + NB);                     // NN int       | one memset
  float*  agg  = (float*)((char*)(csr + NN) +          // NN*64 f32  --+
                          (((size_t)(uintptr_t)(csr + NN) & 15) ? 16 - ((size_t)(uintptr_t)(csr + NN) & 15) : 0));

  const dim3 blk(256);

  // zero gbuf + cnt + csr + agg in one contiguous memset
  const size_t zbytes = (char*)(agg + (size_t)NN * 64) - (char*)gbuf;
  hipMemsetAsync(gbuf, 0, zbytes, stream);

  // stage 1: prep(72) | hist
  const int nPrep = (3 * 64 * 96) / 256;              // 72
  const int nHist = (NE + 255) / 256;
  k_init1<<<nPrep + nHist, blk, 0, stream>>>(conv_w, wt, eidx, csr, NE, nPrep);

  k_scan_fast<<<1, 1024, 0, stream>>>(csr, NN);

  // stage 2: XCD-partitioned scatter | embed, interleaved per 32-block group
  const int ngroups = 261;                            // 24 scat + 8 emb per group
  const int nOrd = ngroups * 3;                       // ordinals per role
  const int nEmb = ngroups * 8;
  k_combo<<<ngroups * 32, blk, 0, stream>>>(
      eidx, ea, csr, edata, x,
      ne_w1, ne_b1, ne_g1, ne_be1, ne_w2, ne_b2, ne_g2, ne_be2,
      h, hb, NN, NE, nOrd, nEmb * 4, 8.0f / (float)NN);

  for (int l = 0; l < 3; l++) {
    k_edge_packed<<<4096, blk, 0, stream>>>(
        hb, agg, edata, wt + (size_t)l * 64 * 96,
        conv_b + l * 64, conv_mg + l * 64, conv_mb + l * 64, NCH, NE);
    k_node_update<<<(NN * 64 + 255) / 256, blk, 0, stream>>>(
        h, hb, agg, csr, conv_ng + l * 64, conv_nb + l * 64,
        out_ng + l * 64, out_nb + l * 64, NN, (l < 2) ? 1 : 0);
  }

  {
    const int chunk = 32;
    const int nwaves = (NN + chunk - 1) / chunk;
    const int nblocks = (nwaves * 64 + 255) / 256;
    k_pool_seg<<<nblocks, blk, 0, stream>>>(h, batch, gbuf, cnt, NN, chunk);
  }
  k_head<<<(NB + 3) / 4, blk, 0, stream>>>(gbuf, cnt, m_w1, m_b1, m_g1, m_be1,
                                           m_w2, m_b2, m_g2, m_be2, m_w3, m_b3,
                                           outp, NB);
}